// Round 1
// baseline (386.453 us; speedup 1.0000x reference)
//
#include <hip/hip_runtime.h>
#include <hip/hip_bf16.h>

// Problem: N=4096, Dx=512, Dz=64.
// out[0]=total, out[1]=rank_loss, out[2]=pairdist_loss (f32).
//
// Pipeline:
//   1. prep (barrier-free): one wave per row; float4 loads, shuffle-only
//      reductions, packed bf16 ushort4 stores; inits qstats.
//   2. gram_both: 528 symmetric triangular 128-tiles, each block does
//      z-tile (K=64) then x-tile (K=512). BK=64 PER BARRIER (two 32-col
//      sub-tiles per buffer, m97-verified LDS layout each). LDS-staged
//      coalesced uint4 dist writes; mirror tile via LDS transpose restage.
//      q0=min(floor(d*qscale),65535), qscale 1024 (x) / 2048 (z).
//   3. rank kernel v2: 4096 blocks x 256 thr, ONE row/block (was 4):
//      - no next-row register prefetch, no oxp/ozp arrival cache ->
//        VGPR <= 64 via __launch_bounds__(256,8) -> 8 blocks/CU resident
//        (was 84 VGPR / 4 blocks -> Occupancy 18%).
//      - count pass: non-returning ds_add (no rtn wait);
//      - final pass: rank taken directly from atomicAdd_rtn on the
//        scanned histogram (base++ arrival) — same intra-bin-arbitrary
//        semantics as before, fewer registers + less VALU packing.
//      Last block (done-counter) computes the 3 output scalars.

#define N 4096
#define DX 512
#define DZ 64
#define NBIN 2048
#define NWRD (NBIN / 2)

typedef __attribute__((ext_vector_type(8))) short short8;
typedef __attribute__((ext_vector_type(4))) float float4v;

// qstats word layout (u32 index):
//   [0..1] rank_acc (u64)  [2..3] pd_acc (double)
//   [4] maxx [5] maxz      [6] minx [7] minz    [8] done-counter
#define ST_MAX 4
#define ST_MIN 6
#define ST_DONE 8

// ---------------- async 16B global -> LDS ----------------
__device__ __forceinline__ void async16(const void* g, void* l) {
  __builtin_amdgcn_global_load_lds(
      (const __attribute__((address_space(1))) unsigned int*)(g),
      (__attribute__((address_space(3))) unsigned int*)(l), 16, 0, 0);
}

// ---------------- prep: barrier-free wave-per-row ----------------
__global__ __launch_bounds__(256) void prep_kernel(
    const float* __restrict__ x, const float* __restrict__ z,
    __hip_bfloat16* __restrict__ xb, __hip_bfloat16* __restrict__ zb,
    float* __restrict__ nx, float* __restrict__ nz,
    unsigned* __restrict__ qstats) {
  int tid = threadIdx.x;
  if (blockIdx.x == 0 && tid < 9)
    qstats[tid] = (tid == 6 || tid == 7) ? 0xFFFFFFFFu : 0u;

  int lane = tid & 63;
  int row = (int)blockIdx.x * 4 + (tid >> 6);

  const float4* xr = (const float4*)(x + (size_t)row * DX);
  float4 a = xr[lane];
  float4 b = xr[lane + 64];
  float s = a.x * a.x + a.y * a.y + a.z * a.z + a.w * a.w +
            b.x * b.x + b.y * b.y + b.z * b.z + b.w * b.w;
#pragma unroll
  for (int d = 32; d; d >>= 1) s += __shfl_xor(s, d, 64);
  if (lane == 0) nx[row] = s;

  ushort4 pa, pb;
  pa.x = __bfloat16_as_ushort(__float2bfloat16(a.x));
  pa.y = __bfloat16_as_ushort(__float2bfloat16(a.y));
  pa.z = __bfloat16_as_ushort(__float2bfloat16(a.z));
  pa.w = __bfloat16_as_ushort(__float2bfloat16(a.w));
  pb.x = __bfloat16_as_ushort(__float2bfloat16(b.x));
  pb.y = __bfloat16_as_ushort(__float2bfloat16(b.y));
  pb.z = __bfloat16_as_ushort(__float2bfloat16(b.z));
  pb.w = __bfloat16_as_ushort(__float2bfloat16(b.w));
  ushort4* xbo = (ushort4*)(xb + (size_t)row * DX);
  xbo[lane] = pa;
  xbo[lane + 64] = pb;

  float4 c = {0.f, 0.f, 0.f, 0.f};
  if (lane < 16) c = ((const float4*)(z + (size_t)row * DZ))[lane];
  float sz = c.x * c.x + c.y * c.y + c.z * c.z + c.w * c.w;
#pragma unroll
  for (int d = 32; d; d >>= 1) sz += __shfl_xor(sz, d, 64);
  if (lane == 0) nz[row] = sz;
  if (lane < 16) {
    ushort4 pc;
    pc.x = __bfloat16_as_ushort(__float2bfloat16(c.x));
    pc.y = __bfloat16_as_ushort(__float2bfloat16(c.y));
    pc.z = __bfloat16_as_ushort(__float2bfloat16(c.z));
    pc.w = __bfloat16_as_ushort(__float2bfloat16(c.w));
    ((ushort4*)(zb + (size_t)row * DZ))[lane] = pc;
  }
}

// ------- bf16 MFMA Gram, BK=64/barrier, symmetric triangular grid --------
#define TILE 128
#define BK 64     // staged K per barrier (two 32-col sub-tiles)
#define PADW 132  // ctile row stride in u16 (66 words, 8B-aligned b64)
#define NT 32
#define NTRI 528

// smem layout (65536 B total):
//   buffer b (b=0,1) at b*32768:
//     A-half0 @0, A-half1 @8192, B-half0 @16384, B-half1 @24576 (each 8 KB,
//     [128][32] bf16 — identical bank layout to the m97-verified BK=32 tile)
//   ctile aliases smem[0..33791] after the K-loop.
//   mmx aliases smem[0..31] in the final (barrier-separated) reduce phase.

__device__ __forceinline__ void gram_tile(
    const __hip_bfloat16* __restrict__ Abf, const float* __restrict__ norms,
    unsigned short* __restrict__ distq, int K, float qscale,
    unsigned* __restrict__ qstats, int slot, int by, int bx, char* smem) {
  unsigned short* ctile = (unsigned short*)smem;
  unsigned* mmx = (unsigned*)smem;

  int tid = threadIdx.x;
  int wave = tid >> 6, lane = tid & 63;
  int wr = wave >> 1, wc = wave & 1;
  int quad = lane >> 4, l15 = lane & 15;

  int rowBase = by * TILE;
  int colBase = bx * TILE;

  float4v acc[4][4];
#pragma unroll
  for (int mi = 0; mi < 4; ++mi)
#pragma unroll
    for (int ni = 0; ni < 4; ++ni) {
      float4v zv = {0.f, 0.f, 0.f, 0.f};
      acc[mi][ni] = zv;
    }

  const char* Ab = (const char*)Abf;
  const size_t rb = (size_t)K * 2;
  int chunk0 = wave * 2, chunk1 = wave * 2 + 1;
  int rl = lane >> 2;
  int cl = (lane & 3) * 16;

  // stage BK=64 chunk (two 32-col halves) into buffer b
  auto stage = [&](int kc, int b) {
#pragma unroll
    for (int h = 0; h < 2; ++h) {
      const char* base = Ab + (size_t)(kc + h * 32) * 2 + cl;
      short* sA = (short*)(smem + b * 32768 + h * 8192);
      short* sB = (short*)(smem + b * 32768 + 16384 + h * 8192);
      async16(base + (size_t)(rowBase + chunk0 * 16 + rl) * rb,
              &sA[chunk0 * 512]);
      async16(base + (size_t)(rowBase + chunk1 * 16 + rl) * rb,
              &sA[chunk1 * 512]);
      async16(base + (size_t)(colBase + chunk0 * 16 + rl) * rb,
              &sB[chunk0 * 512]);
      async16(base + (size_t)(colBase + chunk1 * 16 + rl) * rb,
              &sB[chunk1 * 512]);
    }
  };

  stage(0, 0);
  int ib = 0;
  for (int kc = 0; kc < K; kc += BK, ib ^= 1) {
    __syncthreads();  // drains current buf's staging; prev readers done
    if (kc + BK < K) stage(kc + BK, ib ^ 1);

#pragma unroll
    for (int h = 0; h < 2; ++h) {
      const short* As = (const short*)(smem + ib * 32768 + h * 8192);
      const short* Bs = (const short*)(smem + ib * 32768 + 16384 + h * 8192);
      short8 a[4], b[4];
#pragma unroll
      for (int mi = 0; mi < 4; ++mi)
        a[mi] =
            *(const short8*)(&As[(wr * 64 + mi * 16 + l15) * 32 + quad * 8]);
#pragma unroll
      for (int ni = 0; ni < 4; ++ni)
        b[ni] =
            *(const short8*)(&Bs[(wc * 64 + ni * 16 + l15) * 32 + quad * 8]);
#pragma unroll
      for (int mi = 0; mi < 4; ++mi)
#pragma unroll
        for (int ni = 0; ni < 4; ++ni)
          acc[mi][ni] = __builtin_amdgcn_mfma_f32_16x16x32_bf16(
              a[mi], b[ni], acc[mi][ni], 0, 0, 0);
    }
  }
  __syncthreads();  // all staging reads done before ctile aliasing write

  // quantize: stage [row][col] in LDS + keep packed u64 per column
  unsigned mn = 0xFFFFu, mx = 0u;
  unsigned long long qp[4][4];
#pragma unroll
  for (int mi = 0; mi < 4; ++mi) {
#pragma unroll
    for (int ni = 0; ni < 4; ++ni) {
      int colL = wc * 64 + ni * 16 + l15;
      float ncol = norms[colBase + colL];
      unsigned long long pk = 0ull;
#pragma unroll
      for (int r = 0; r < 4; ++r) {
        int rowL = wr * 64 + mi * 16 + quad * 4 + r;
        int row = rowBase + rowL;
        float sq = norms[row] + ncol - 2.0f * acc[mi][ni][r];
        float d = sq > 0.f ? sqrtf(sq) : 0.f;
        if (row == colBase + colL) d = 0.f;
        unsigned q = (unsigned)(d * qscale);
        q = q > 65535u ? 65535u : q;
        ctile[rowL * PADW + colL] = (unsigned short)q;
        pk |= (unsigned long long)q << (16 * r);
        mx = max(mx, q);
        mn = min(mn, (row == colBase + colL) ? 0xFFFFu : q);
      }
      qp[mi][ni] = pk;
    }
  }
  __syncthreads();

  // pass A: upper tile, coalesced uint4 rows
  {
    const unsigned* cw = (const unsigned*)ctile;
    int i0 = tid >> 4, k4 = (tid & 15) * 4;
#pragma unroll
    for (int s = 0; s < 8; ++s) {
      int i = s * 16 + i0;
      int wb = i * (PADW / 2) + k4;
      uint4 v;
      v.x = cw[wb + 0];
      v.y = cw[wb + 1];
      v.z = cw[wb + 2];
      v.w = cw[wb + 3];
      *(uint4*)(distq + (size_t)(rowBase + i) * N + colBase + (tid & 15) * 8) =
          v;
    }
  }

  // pass B: mirror tile via transposed restage (off-diag only)
  if (by != bx) {
    __syncthreads();
#pragma unroll
    for (int mi = 0; mi < 4; ++mi)
#pragma unroll
      for (int ni = 0; ni < 4; ++ni) {
        int colL = wc * 64 + ni * 16 + l15;
        int rowL0 = wr * 64 + mi * 16 + quad * 4;
        *(unsigned long long*)&ctile[colL * PADW + rowL0] = qp[mi][ni];
      }
    __syncthreads();
    const unsigned* cw = (const unsigned*)ctile;
    int j0 = tid >> 4, k4 = (tid & 15) * 4;
#pragma unroll
    for (int s = 0; s < 8; ++s) {
      int j = s * 16 + j0;
      int wb = j * (PADW / 2) + k4;
      uint4 v;
      v.x = cw[wb + 0];
      v.y = cw[wb + 1];
      v.z = cw[wb + 2];
      v.w = cw[wb + 3];
      *(uint4*)(distq + (size_t)(colBase + j) * N + rowBase + (tid & 15) * 8) =
          v;
    }
  }

  // block-level min/max reduce -> 2 device atomics per tile
#pragma unroll
  for (int d = 32; d; d >>= 1) {
    mn = min(mn, (unsigned)__shfl_xor((int)mn, d, 64));
    mx = max(mx, (unsigned)__shfl_xor((int)mx, d, 64));
  }
  __syncthreads();  // ctile/pass-B reads done; mmx aliasing safe
  if (lane == 0) {
    mmx[wave] = mn;
    mmx[4 + wave] = mx;
  }
  __syncthreads();
  if (tid == 0) {
    unsigned bmn = min(min(mmx[0], mmx[1]), min(mmx[2], mmx[3]));
    unsigned bmx = max(max(mmx[4], mmx[5]), max(mmx[6], mmx[7]));
    atomicMin(&qstats[ST_MIN + slot], bmn);
    atomicMax(&qstats[ST_MAX + slot], bmx);
  }
}

__global__ __launch_bounds__(256) void gram_both_kernel(
    const __hip_bfloat16* __restrict__ xb, const __hip_bfloat16* __restrict__ zb,
    const float* __restrict__ nx, const float* __restrict__ nz,
    unsigned short* __restrict__ qx16, unsigned short* __restrict__ qz16,
    unsigned* __restrict__ qstats) {
  __shared__ alignas(16) char smem[65536];  // dbuf staging; ctile/mmx aliased

  // compact upper-triangular decode: row-major rows by=0..31, len 32-by
  int idx = (int)blockIdx.x;
  int by = (int)((65.0f - sqrtf(4225.0f - 8.0f * (float)idx)) * 0.5f);
  while (((by + 1) * (65 - (by + 1))) / 2 <= idx) ++by;
  while ((by * (65 - by)) / 2 > idx) --by;
  int bx = by + (idx - (by * (65 - by)) / 2);

  gram_tile(zb, nz, qz16, DZ, 2048.0f, qstats, 1, by, bx, smem);
  __syncthreads();
  gram_tile(xb, nx, qx16, DX, 1024.0f, qstats, 0, by, bx, smem);
}

// ---------------- counting-based per-row ranks (1 row / block) ----------
__device__ __forceinline__ int hsw(int w) { return w ^ ((w >> 5) & 31); }

__global__ __launch_bounds__(256, 8) void rank_kernel(
    const unsigned short* __restrict__ qx,
    const unsigned short* __restrict__ qz, unsigned* __restrict__ qstats,
    float* __restrict__ out) {
  __shared__ unsigned histX[NWRD];
  __shared__ unsigned histZ[NWRD];
  __shared__ unsigned xch[32];

  unsigned long long* rank_acc = (unsigned long long*)qstats;
  double* pd_acc = (double*)(qstats + 2);

  int t = threadIdx.x, lane = t & 63, wv = t >> 6;
  int row = (int)blockIdx.x;

  float lox = (float)(int)qstats[ST_MIN + 0];
  float scx = (float)(NBIN - 1) /
              (float)(int)max(1u, qstats[ST_MAX + 0] - qstats[ST_MIN + 0]);
  float loz = (float)(int)qstats[ST_MIN + 1];
  float scz = (float)(NBIN - 1) /
              (float)(int)max(1u, qstats[ST_MAX + 1] - qstats[ST_MIN + 1]);

  const uint4* px = (const uint4*)(qx + (size_t)row * N);
  const uint4* pz = (const uint4*)(qz + (size_t)row * N);

  uint4 cxa = px[t * 2], cxb = px[t * 2 + 1];
  uint4 cza = pz[t * 2], czb = pz[t * 2 + 1];

#pragma unroll
  for (int i = 0; i < 4; ++i) {
    histX[t + 256 * i] = 0u;
    histZ[t + 256 * i] = 0u;
  }

  unsigned xw[8] = {cxa.x, cxa.y, cxa.z, cxa.w, cxb.x, cxb.y, cxb.z, cxb.w};
  unsigned zw[8] = {cza.x, cza.y, cza.z, cza.w, czb.x, czb.y, czb.z, czb.w};

  // pairdist accumulation (no LDS) fills the gap before the zeroing barrier
  float pd = 0.f;
#pragma unroll
  for (int c = 0; c < 16; ++c) {
    unsigned qxv = (xw[c >> 1] >> ((c & 1) * 16)) & 0xFFFFu;
    unsigned qzv = (zw[c >> 1] >> ((c & 1) * 16)) & 0xFFFFu;
    // dz-dx = (qz - 2*qx - 0.5)/2048
    float tv = (float)(int)qzv - 2.0f * (float)(int)qxv - 0.5f;
    pd += tv * tv;
  }
  __syncthreads();  // zeros visible to all waves

  // count pass: non-returning LDS adds (ds_add, no rtn wait)
#pragma unroll
  for (int c = 0; c < 16; ++c) {
    unsigned qxv = (xw[c >> 1] >> ((c & 1) * 16)) & 0xFFFFu;
    unsigned qzv = (zw[c >> 1] >> ((c & 1) * 16)) & 0xFFFFu;
    unsigned bx = (unsigned)(int)fminf(
        fmaxf(((float)(int)qxv - lox) * scx, 0.0f), (float)(NBIN - 1));
    unsigned bz = (unsigned)(int)fminf(
        fmaxf(((float)(int)qzv - loz) * scz, 0.0f), (float)(NBIN - 1));
    atomicAdd(&histX[hsw((int)(bx >> 1))], 1u << ((bx & 1) * 16));
    atomicAdd(&histZ[hsw((int)(bz >> 1))], 1u << ((bz & 1) * 16));
  }
  __syncthreads();

  // dual exclusive scan: waves 0-1 -> histX, waves 2-3 -> histZ
  {
    unsigned* h = (wv < 2) ? histX : histZ;
    int t2 = t & 127;
    int wb = t2 * 8;
    unsigned run = 0;
#pragma unroll
    for (int c = 0; c < 8; ++c) {
      int w = hsw(wb + c);
      unsigned v = h[w];
      unsigned lo = v & 0xFFFFu;
      h[w] = run | ((run + lo) << 16);
      run += lo + (v >> 16);
    }
    unsigned incl = run;
#pragma unroll
    for (int d = 1; d < 64; d <<= 1) {
      unsigned o = (unsigned)__shfl_up((int)incl, d, 64);
      if (lane >= d) incl += o;
    }
    if (lane == 63) xch[16 + wv] = incl;
    __syncthreads();
    unsigned base = incl - run;
    if (wv & 1) base += xch[16 + (wv - 1)];
    unsigned add = base * 0x10001u;
#pragma unroll
    for (int c = 0; c < 8; ++c) h[hsw(wb + c)] += add;
  }
  __syncthreads();

  // final pass: rank = returned base (base++ arrival within bin)
  int rsum = 0;
#pragma unroll
  for (int c = 0; c < 16; ++c) {
    unsigned qxv = (xw[c >> 1] >> ((c & 1) * 16)) & 0xFFFFu;
    unsigned qzv = (zw[c >> 1] >> ((c & 1) * 16)) & 0xFFFFu;
    unsigned bx = (unsigned)(int)fminf(
        fmaxf(((float)(int)qxv - lox) * scx, 0.0f), (float)(NBIN - 1));
    unsigned bz = (unsigned)(int)fminf(
        fmaxf(((float)(int)qzv - loz) * scz, 0.0f), (float)(NBIN - 1));
    unsigned shx = (bx & 1) * 16, shz = (bz & 1) * 16;
    int rx = (int)((atomicAdd(&histX[hsw((int)(bx >> 1))], 1u << shx) >> shx) &
                   0xFFFFu);
    int rz = (int)((atomicAdd(&histZ[hsw((int)(bz >> 1))], 1u << shz) >> shz) &
                   0xFFFFu);
    int d = rx - rz;
    rsum += d < 0 ? -d : d;
  }

  // block reduce + global atomics + last-block finalize
#pragma unroll
  for (int d = 32; d; d >>= 1) {
    rsum += __shfl_xor(rsum, d, 64);
    pd += __shfl_xor(pd, d, 64);
  }
  if (lane == 0) {
    xch[wv] = (unsigned)rsum;
    ((float*)xch)[8 + wv] = pd;
  }
  __syncthreads();
  if (t == 0) {
    unsigned long long rtot =
        (unsigned long long)xch[0] + xch[1] + xch[2] + xch[3];
    float ptot = ((float*)xch)[8] + ((float*)xch)[9] + ((float*)xch)[10] +
                 ((float*)xch)[11];
    atomicAdd(rank_acc, rtot);
    atomicAdd(pd_acc, (double)ptot);
    __threadfence();
    unsigned old = atomicAdd(&qstats[ST_DONE], 1u);
    if (old == (unsigned)gridDim.x - 1u) {
      unsigned long long rall = atomicAdd(rank_acc, 0ull);
      double pall = atomicAdd(pd_acc, 0.0);
      double inv = 1.0 / ((double)N * (double)N);
      double rank_loss = (double)rall * inv / 32.0;  // K = 32
      double pdv = pall * inv / (2048.0 * 2048.0);   // undo q scaling
      out[0] = (float)(rank_loss + 0.5 * pdv);
      out[1] = (float)rank_loss;
      out[2] = (float)pdv;
    }
  }
}

// ---------------- launch ----------------
extern "C" void kernel_launch(void* const* d_in, const int* in_sizes, int n_in,
                              void* d_out, int out_size, void* d_ws,
                              size_t ws_size, hipStream_t stream) {
  (void)in_sizes; (void)n_in; (void)out_size; (void)ws_size;
  const float* x = (const float*)d_in[0];
  const float* z = (const float*)d_in[1];
  float* out = (float*)d_out;

  char* w = (char*)d_ws;
  unsigned short* qx16 = (unsigned short*)(w);             // 32 MB
  unsigned short* qz16 = (unsigned short*)(w + 33554432);  // 32 MB
  __hip_bfloat16* xb = (__hip_bfloat16*)(w + 67108864);    // 4 MB
  __hip_bfloat16* zb = (__hip_bfloat16*)(w + 71303168);    // 0.5 MB
  float* nx = (float*)(w + 71827456);
  float* nz = (float*)(w + 71843840);
  unsigned* qstats = (unsigned*)(w + 71860224);

  prep_kernel<<<N / 4, 256, 0, stream>>>(x, z, xb, zb, nx, nz, qstats);

  gram_both_kernel<<<NTRI, 256, 0, stream>>>(xb, zb, nx, nz, qx16, qz16,
                                             qstats);

  rank_kernel<<<N, 256, 0, stream>>>(qx16, qz16, qstats, out);
}

// Round 2
// 341.446 us; speedup vs baseline: 1.1318x; 1.1318x over previous
//
#include <hip/hip_runtime.h>
#include <hip/hip_bf16.h>

// Problem: N=4096, Dx=512, Dz=64.
// out[0]=total, out[1]=rank_loss, out[2]=pairdist_loss (f32).
//
// Pipeline:
//   1. prep (barrier-free): one wave per row; float4 loads, shuffle-only
//      reductions, packed bf16 ushort4 stores; inits qstats.
//   2. gram_both: 528 symmetric triangular 128-tiles, each block does
//      z-tile (K=64) then x-tile (K=512). BK=64 PER BARRIER (two 32-col
//      sub-tiles per buffer, m97-verified LDS layout each). LDS-staged
//      coalesced uint4 dist writes; mirror tile via LDS transpose restage.
//      q0=min(floor(d*qscale),65535), qscale 1024 (x) / 2048 (z).
//   3. rank kernel v3: 4096 blocks x 256 thr, ONE row/block.
//      __launch_bounds__(256, 6): 85-VGPR budget covers the natural live
//      set (~80) -> NO scratch spill. Round-1's (256,8) forced a 64-VGPR
//      budget below the live set -> 580 MB of scratch HBM traffic,
//      VALUBusy 7%, 280 us. 6 waves/SIMD resident is 4x round-0's 1.45.
//      - count pass: non-returning ds_add (no rtn wait);
//      - final pass: rank taken directly from atomicAdd_rtn on the
//        scanned histogram (base++ arrival, intra-bin-arbitrary order —
//        verified absmax 0.0 in round 1).
//      Last block (done-counter) computes the 3 output scalars.

#define N 4096
#define DX 512
#define DZ 64
#define NBIN 2048
#define NWRD (NBIN / 2)

typedef __attribute__((ext_vector_type(8))) short short8;
typedef __attribute__((ext_vector_type(4))) float float4v;

// qstats word layout (u32 index):
//   [0..1] rank_acc (u64)  [2..3] pd_acc (double)
//   [4] maxx [5] maxz      [6] minx [7] minz    [8] done-counter
#define ST_MAX 4
#define ST_MIN 6
#define ST_DONE 8

// ---------------- async 16B global -> LDS ----------------
__device__ __forceinline__ void async16(const void* g, void* l) {
  __builtin_amdgcn_global_load_lds(
      (const __attribute__((address_space(1))) unsigned int*)(g),
      (__attribute__((address_space(3))) unsigned int*)(l), 16, 0, 0);
}

// ---------------- prep: barrier-free wave-per-row ----------------
__global__ __launch_bounds__(256) void prep_kernel(
    const float* __restrict__ x, const float* __restrict__ z,
    __hip_bfloat16* __restrict__ xb, __hip_bfloat16* __restrict__ zb,
    float* __restrict__ nx, float* __restrict__ nz,
    unsigned* __restrict__ qstats) {
  int tid = threadIdx.x;
  if (blockIdx.x == 0 && tid < 9)
    qstats[tid] = (tid == 6 || tid == 7) ? 0xFFFFFFFFu : 0u;

  int lane = tid & 63;
  int row = (int)blockIdx.x * 4 + (tid >> 6);

  const float4* xr = (const float4*)(x + (size_t)row * DX);
  float4 a = xr[lane];
  float4 b = xr[lane + 64];
  float s = a.x * a.x + a.y * a.y + a.z * a.z + a.w * a.w +
            b.x * b.x + b.y * b.y + b.z * b.z + b.w * b.w;
#pragma unroll
  for (int d = 32; d; d >>= 1) s += __shfl_xor(s, d, 64);
  if (lane == 0) nx[row] = s;

  ushort4 pa, pb;
  pa.x = __bfloat16_as_ushort(__float2bfloat16(a.x));
  pa.y = __bfloat16_as_ushort(__float2bfloat16(a.y));
  pa.z = __bfloat16_as_ushort(__float2bfloat16(a.z));
  pa.w = __bfloat16_as_ushort(__float2bfloat16(a.w));
  pb.x = __bfloat16_as_ushort(__float2bfloat16(b.x));
  pb.y = __bfloat16_as_ushort(__float2bfloat16(b.y));
  pb.z = __bfloat16_as_ushort(__float2bfloat16(b.z));
  pb.w = __bfloat16_as_ushort(__float2bfloat16(b.w));
  ushort4* xbo = (ushort4*)(xb + (size_t)row * DX);
  xbo[lane] = pa;
  xbo[lane + 64] = pb;

  float4 c = {0.f, 0.f, 0.f, 0.f};
  if (lane < 16) c = ((const float4*)(z + (size_t)row * DZ))[lane];
  float sz = c.x * c.x + c.y * c.y + c.z * c.z + c.w * c.w;
#pragma unroll
  for (int d = 32; d; d >>= 1) sz += __shfl_xor(sz, d, 64);
  if (lane == 0) nz[row] = sz;
  if (lane < 16) {
    ushort4 pc;
    pc.x = __bfloat16_as_ushort(__float2bfloat16(c.x));
    pc.y = __bfloat16_as_ushort(__float2bfloat16(c.y));
    pc.z = __bfloat16_as_ushort(__float2bfloat16(c.z));
    pc.w = __bfloat16_as_ushort(__float2bfloat16(c.w));
    ((ushort4*)(zb + (size_t)row * DZ))[lane] = pc;
  }
}

// ------- bf16 MFMA Gram, BK=64/barrier, symmetric triangular grid --------
#define TILE 128
#define BK 64     // staged K per barrier (two 32-col sub-tiles)
#define PADW 132  // ctile row stride in u16 (66 words, 8B-aligned b64)
#define NT 32
#define NTRI 528

// smem layout (65536 B total):
//   buffer b (b=0,1) at b*32768:
//     A-half0 @0, A-half1 @8192, B-half0 @16384, B-half1 @24576 (each 8 KB,
//     [128][32] bf16 — identical bank layout to the m97-verified BK=32 tile)
//   ctile aliases smem[0..33791] after the K-loop.
//   mmx aliases smem[0..31] in the final (barrier-separated) reduce phase.

__device__ __forceinline__ void gram_tile(
    const __hip_bfloat16* __restrict__ Abf, const float* __restrict__ norms,
    unsigned short* __restrict__ distq, int K, float qscale,
    unsigned* __restrict__ qstats, int slot, int by, int bx, char* smem) {
  unsigned short* ctile = (unsigned short*)smem;
  unsigned* mmx = (unsigned*)smem;

  int tid = threadIdx.x;
  int wave = tid >> 6, lane = tid & 63;
  int wr = wave >> 1, wc = wave & 1;
  int quad = lane >> 4, l15 = lane & 15;

  int rowBase = by * TILE;
  int colBase = bx * TILE;

  float4v acc[4][4];
#pragma unroll
  for (int mi = 0; mi < 4; ++mi)
#pragma unroll
    for (int ni = 0; ni < 4; ++ni) {
      float4v zv = {0.f, 0.f, 0.f, 0.f};
      acc[mi][ni] = zv;
    }

  const char* Ab = (const char*)Abf;
  const size_t rb = (size_t)K * 2;
  int chunk0 = wave * 2, chunk1 = wave * 2 + 1;
  int rl = lane >> 2;
  int cl = (lane & 3) * 16;

  // stage BK=64 chunk (two 32-col halves) into buffer b
  auto stage = [&](int kc, int b) {
#pragma unroll
    for (int h = 0; h < 2; ++h) {
      const char* base = Ab + (size_t)(kc + h * 32) * 2 + cl;
      short* sA = (short*)(smem + b * 32768 + h * 8192);
      short* sB = (short*)(smem + b * 32768 + 16384 + h * 8192);
      async16(base + (size_t)(rowBase + chunk0 * 16 + rl) * rb,
              &sA[chunk0 * 512]);
      async16(base + (size_t)(rowBase + chunk1 * 16 + rl) * rb,
              &sA[chunk1 * 512]);
      async16(base + (size_t)(colBase + chunk0 * 16 + rl) * rb,
              &sB[chunk0 * 512]);
      async16(base + (size_t)(colBase + chunk1 * 16 + rl) * rb,
              &sB[chunk1 * 512]);
    }
  };

  stage(0, 0);
  int ib = 0;
  for (int kc = 0; kc < K; kc += BK, ib ^= 1) {
    __syncthreads();  // drains current buf's staging; prev readers done
    if (kc + BK < K) stage(kc + BK, ib ^ 1);

#pragma unroll
    for (int h = 0; h < 2; ++h) {
      const short* As = (const short*)(smem + ib * 32768 + h * 8192);
      const short* Bs = (const short*)(smem + ib * 32768 + 16384 + h * 8192);
      short8 a[4], b[4];
#pragma unroll
      for (int mi = 0; mi < 4; ++mi)
        a[mi] =
            *(const short8*)(&As[(wr * 64 + mi * 16 + l15) * 32 + quad * 8]);
#pragma unroll
      for (int ni = 0; ni < 4; ++ni)
        b[ni] =
            *(const short8*)(&Bs[(wc * 64 + ni * 16 + l15) * 32 + quad * 8]);
#pragma unroll
      for (int mi = 0; mi < 4; ++mi)
#pragma unroll
        for (int ni = 0; ni < 4; ++ni)
          acc[mi][ni] = __builtin_amdgcn_mfma_f32_16x16x32_bf16(
              a[mi], b[ni], acc[mi][ni], 0, 0, 0);
    }
  }
  __syncthreads();  // all staging reads done before ctile aliasing write

  // quantize: stage [row][col] in LDS + keep packed u64 per column
  unsigned mn = 0xFFFFu, mx = 0u;
  unsigned long long qp[4][4];
#pragma unroll
  for (int mi = 0; mi < 4; ++mi) {
#pragma unroll
    for (int ni = 0; ni < 4; ++ni) {
      int colL = wc * 64 + ni * 16 + l15;
      float ncol = norms[colBase + colL];
      unsigned long long pk = 0ull;
#pragma unroll
      for (int r = 0; r < 4; ++r) {
        int rowL = wr * 64 + mi * 16 + quad * 4 + r;
        int row = rowBase + rowL;
        float sq = norms[row] + ncol - 2.0f * acc[mi][ni][r];
        float d = sq > 0.f ? sqrtf(sq) : 0.f;
        if (row == colBase + colL) d = 0.f;
        unsigned q = (unsigned)(d * qscale);
        q = q > 65535u ? 65535u : q;
        ctile[rowL * PADW + colL] = (unsigned short)q;
        pk |= (unsigned long long)q << (16 * r);
        mx = max(mx, q);
        mn = min(mn, (row == colBase + colL) ? 0xFFFFu : q);
      }
      qp[mi][ni] = pk;
    }
  }
  __syncthreads();

  // pass A: upper tile, coalesced uint4 rows
  {
    const unsigned* cw = (const unsigned*)ctile;
    int i0 = tid >> 4, k4 = (tid & 15) * 4;
#pragma unroll
    for (int s = 0; s < 8; ++s) {
      int i = s * 16 + i0;
      int wb = i * (PADW / 2) + k4;
      uint4 v;
      v.x = cw[wb + 0];
      v.y = cw[wb + 1];
      v.z = cw[wb + 2];
      v.w = cw[wb + 3];
      *(uint4*)(distq + (size_t)(rowBase + i) * N + colBase + (tid & 15) * 8) =
          v;
    }
  }

  // pass B: mirror tile via transposed restage (off-diag only)
  if (by != bx) {
    __syncthreads();
#pragma unroll
    for (int mi = 0; mi < 4; ++mi)
#pragma unroll
      for (int ni = 0; ni < 4; ++ni) {
        int colL = wc * 64 + ni * 16 + l15;
        int rowL0 = wr * 64 + mi * 16 + quad * 4;
        *(unsigned long long*)&ctile[colL * PADW + rowL0] = qp[mi][ni];
      }
    __syncthreads();
    const unsigned* cw = (const unsigned*)ctile;
    int j0 = tid >> 4, k4 = (tid & 15) * 4;
#pragma unroll
    for (int s = 0; s < 8; ++s) {
      int j = s * 16 + j0;
      int wb = j * (PADW / 2) + k4;
      uint4 v;
      v.x = cw[wb + 0];
      v.y = cw[wb + 1];
      v.z = cw[wb + 2];
      v.w = cw[wb + 3];
      *(uint4*)(distq + (size_t)(colBase + j) * N + rowBase + (tid & 15) * 8) =
          v;
    }
  }

  // block-level min/max reduce -> 2 device atomics per tile
#pragma unroll
  for (int d = 32; d; d >>= 1) {
    mn = min(mn, (unsigned)__shfl_xor((int)mn, d, 64));
    mx = max(mx, (unsigned)__shfl_xor((int)mx, d, 64));
  }
  __syncthreads();  // ctile/pass-B reads done; mmx aliasing safe
  if (lane == 0) {
    mmx[wave] = mn;
    mmx[4 + wave] = mx;
  }
  __syncthreads();
  if (tid == 0) {
    unsigned bmn = min(min(mmx[0], mmx[1]), min(mmx[2], mmx[3]));
    unsigned bmx = max(max(mmx[4], mmx[5]), max(mmx[6], mmx[7]));
    atomicMin(&qstats[ST_MIN + slot], bmn);
    atomicMax(&qstats[ST_MAX + slot], bmx);
  }
}

__global__ __launch_bounds__(256) void gram_both_kernel(
    const __hip_bfloat16* __restrict__ xb, const __hip_bfloat16* __restrict__ zb,
    const float* __restrict__ nx, const float* __restrict__ nz,
    unsigned short* __restrict__ qx16, unsigned short* __restrict__ qz16,
    unsigned* __restrict__ qstats) {
  __shared__ alignas(16) char smem[65536];  // dbuf staging; ctile/mmx aliased

  // compact upper-triangular decode: row-major rows by=0..31, len 32-by
  int idx = (int)blockIdx.x;
  int by = (int)((65.0f - sqrtf(4225.0f - 8.0f * (float)idx)) * 0.5f);
  while (((by + 1) * (65 - (by + 1))) / 2 <= idx) ++by;
  while ((by * (65 - by)) / 2 > idx) --by;
  int bx = by + (idx - (by * (65 - by)) / 2);

  gram_tile(zb, nz, qz16, DZ, 2048.0f, qstats, 1, by, bx, smem);
  __syncthreads();
  gram_tile(xb, nx, qx16, DX, 1024.0f, qstats, 0, by, bx, smem);
}

// ---------------- counting-based per-row ranks (1 row / block) ----------
__device__ __forceinline__ int hsw(int w) { return w ^ ((w >> 5) & 31); }

__global__ __launch_bounds__(256, 6) void rank_kernel(
    const unsigned short* __restrict__ qx,
    const unsigned short* __restrict__ qz, unsigned* __restrict__ qstats,
    float* __restrict__ out) {
  __shared__ unsigned histX[NWRD];
  __shared__ unsigned histZ[NWRD];
  __shared__ unsigned xch[32];

  unsigned long long* rank_acc = (unsigned long long*)qstats;
  double* pd_acc = (double*)(qstats + 2);

  int t = threadIdx.x, lane = t & 63, wv = t >> 6;
  int row = (int)blockIdx.x;

  float lox = (float)(int)qstats[ST_MIN + 0];
  float scx = (float)(NBIN - 1) /
              (float)(int)max(1u, qstats[ST_MAX + 0] - qstats[ST_MIN + 0]);
  float loz = (float)(int)qstats[ST_MIN + 1];
  float scz = (float)(NBIN - 1) /
              (float)(int)max(1u, qstats[ST_MAX + 1] - qstats[ST_MIN + 1]);

  const uint4* px = (const uint4*)(qx + (size_t)row * N);
  const uint4* pz = (const uint4*)(qz + (size_t)row * N);

  uint4 cxa = px[t * 2], cxb = px[t * 2 + 1];
  uint4 cza = pz[t * 2], czb = pz[t * 2 + 1];

#pragma unroll
  for (int i = 0; i < 4; ++i) {
    histX[t + 256 * i] = 0u;
    histZ[t + 256 * i] = 0u;
  }

  unsigned xw[8] = {cxa.x, cxa.y, cxa.z, cxa.w, cxb.x, cxb.y, cxb.z, cxb.w};
  unsigned zw[8] = {cza.x, cza.y, cza.z, cza.w, czb.x, czb.y, czb.z, czb.w};

  // pairdist accumulation (no LDS) fills the gap before the zeroing barrier
  float pd = 0.f;
#pragma unroll
  for (int c = 0; c < 16; ++c) {
    unsigned qxv = (xw[c >> 1] >> ((c & 1) * 16)) & 0xFFFFu;
    unsigned qzv = (zw[c >> 1] >> ((c & 1) * 16)) & 0xFFFFu;
    // dz-dx = (qz - 2*qx - 0.5)/2048
    float tv = (float)(int)qzv - 2.0f * (float)(int)qxv - 0.5f;
    pd += tv * tv;
  }
  __syncthreads();  // zeros visible to all waves

  // count pass: non-returning LDS adds (ds_add, no rtn wait)
#pragma unroll
  for (int c = 0; c < 16; ++c) {
    unsigned qxv = (xw[c >> 1] >> ((c & 1) * 16)) & 0xFFFFu;
    unsigned qzv = (zw[c >> 1] >> ((c & 1) * 16)) & 0xFFFFu;
    unsigned bx = (unsigned)(int)fminf(
        fmaxf(((float)(int)qxv - lox) * scx, 0.0f), (float)(NBIN - 1));
    unsigned bz = (unsigned)(int)fminf(
        fmaxf(((float)(int)qzv - loz) * scz, 0.0f), (float)(NBIN - 1));
    atomicAdd(&histX[hsw((int)(bx >> 1))], 1u << ((bx & 1) * 16));
    atomicAdd(&histZ[hsw((int)(bz >> 1))], 1u << ((bz & 1) * 16));
  }
  __syncthreads();

  // dual exclusive scan: waves 0-1 -> histX, waves 2-3 -> histZ
  {
    unsigned* h = (wv < 2) ? histX : histZ;
    int t2 = t & 127;
    int wb = t2 * 8;
    unsigned run = 0;
#pragma unroll
    for (int c = 0; c < 8; ++c) {
      int w = hsw(wb + c);
      unsigned v = h[w];
      unsigned lo = v & 0xFFFFu;
      h[w] = run | ((run + lo) << 16);
      run += lo + (v >> 16);
    }
    unsigned incl = run;
#pragma unroll
    for (int d = 1; d < 64; d <<= 1) {
      unsigned o = (unsigned)__shfl_up((int)incl, d, 64);
      if (lane >= d) incl += o;
    }
    if (lane == 63) xch[16 + wv] = incl;
    __syncthreads();
    unsigned base = incl - run;
    if (wv & 1) base += xch[16 + (wv - 1)];
    unsigned add = base * 0x10001u;
#pragma unroll
    for (int c = 0; c < 8; ++c) h[hsw(wb + c)] += add;
  }
  __syncthreads();

  // final pass: rank = returned base (base++ arrival within bin)
  int rsum = 0;
#pragma unroll
  for (int c = 0; c < 16; ++c) {
    unsigned qxv = (xw[c >> 1] >> ((c & 1) * 16)) & 0xFFFFu;
    unsigned qzv = (zw[c >> 1] >> ((c & 1) * 16)) & 0xFFFFu;
    unsigned bx = (unsigned)(int)fminf(
        fmaxf(((float)(int)qxv - lox) * scx, 0.0f), (float)(NBIN - 1));
    unsigned bz = (unsigned)(int)fminf(
        fmaxf(((float)(int)qzv - loz) * scz, 0.0f), (float)(NBIN - 1));
    unsigned shx = (bx & 1) * 16, shz = (bz & 1) * 16;
    int rx = (int)((atomicAdd(&histX[hsw((int)(bx >> 1))], 1u << shx) >> shx) &
                   0xFFFFu);
    int rz = (int)((atomicAdd(&histZ[hsw((int)(bz >> 1))], 1u << shz) >> shz) &
                   0xFFFFu);
    int d = rx - rz;
    rsum += d < 0 ? -d : d;
  }

  // block reduce + global atomics + last-block finalize
#pragma unroll
  for (int d = 32; d; d >>= 1) {
    rsum += __shfl_xor(rsum, d, 64);
    pd += __shfl_xor(pd, d, 64);
  }
  if (lane == 0) {
    xch[wv] = (unsigned)rsum;
    ((float*)xch)[8 + wv] = pd;
  }
  __syncthreads();
  if (t == 0) {
    unsigned long long rtot =
        (unsigned long long)xch[0] + xch[1] + xch[2] + xch[3];
    float ptot = ((float*)xch)[8] + ((float*)xch)[9] + ((float*)xch)[10] +
                 ((float*)xch)[11];
    atomicAdd(rank_acc, rtot);
    atomicAdd(pd_acc, (double)ptot);
    __threadfence();
    unsigned old = atomicAdd(&qstats[ST_DONE], 1u);
    if (old == (unsigned)gridDim.x - 1u) {
      unsigned long long rall = atomicAdd(rank_acc, 0ull);
      double pall = atomicAdd(pd_acc, 0.0);
      double inv = 1.0 / ((double)N * (double)N);
      double rank_loss = (double)rall * inv / 32.0;  // K = 32
      double pdv = pall * inv / (2048.0 * 2048.0);   // undo q scaling
      out[0] = (float)(rank_loss + 0.5 * pdv);
      out[1] = (float)rank_loss;
      out[2] = (float)pdv;
    }
  }
}

// ---------------- launch ----------------
extern "C" void kernel_launch(void* const* d_in, const int* in_sizes, int n_in,
                              void* d_out, int out_size, void* d_ws,
                              size_t ws_size, hipStream_t stream) {
  (void)in_sizes; (void)n_in; (void)out_size; (void)ws_size;
  const float* x = (const float*)d_in[0];
  const float* z = (const float*)d_in[1];
  float* out = (float*)d_out;

  char* w = (char*)d_ws;
  unsigned short* qx16 = (unsigned short*)(w);             // 32 MB
  unsigned short* qz16 = (unsigned short*)(w + 33554432);  // 32 MB
  __hip_bfloat16* xb = (__hip_bfloat16*)(w + 67108864);    // 4 MB
  __hip_bfloat16* zb = (__hip_bfloat16*)(w + 71303168);    // 0.5 MB
  float* nx = (float*)(w + 71827456);
  float* nz = (float*)(w + 71843840);
  unsigned* qstats = (unsigned*)(w + 71860224);

  prep_kernel<<<N / 4, 256, 0, stream>>>(x, z, xb, zb, nx, nz, qstats);

  gram_both_kernel<<<NTRI, 256, 0, stream>>>(xb, zb, nx, nz, qx16, qz16,
                                             qstats);

  rank_kernel<<<N, 256, 0, stream>>>(qx16, qz16, qstats, out);
}

// Round 3
// 275.206 us; speedup vs baseline: 1.4042x; 1.2407x over previous
//
#include <hip/hip_runtime.h>
#include <hip/hip_bf16.h>

// Problem: N=4096, Dx=512, Dz=64.
// out[0]=total, out[1]=rank_loss, out[2]=pairdist_loss (f32).
//
// Pipeline:
//   1. prep (barrier-free): one wave per row; float4 loads, shuffle-only
//      reductions, packed bf16 ushort4 stores; inits qstats.
//   2. gram_both: 528 symmetric triangular 128-tiles, each block does
//      z-tile (K=64) then x-tile (K=512). BK=64 PER BARRIER (two 32-col
//      sub-tiles per buffer, m97-verified LDS layout each). LDS-staged
//      coalesced uint4 dist writes; mirror tile via LDS transpose restage.
//      q0=min(floor(d*qscale),65535), qscale 1024 (x) / 2048 (z).
//   3. rank kernel v4: 4096 blocks x 256 thr, ONE row/block, PLAIN
//      __launch_bounds__(256). HW lesson (r1/r2): waves/SIMD is quantized
//      at VGPR={64,128,256}; any min-waves arg >4 forces a 64-VGPR cap,
//      which is below this kernel's ~80-reg live set -> 250-450 MB of
//      scratch spill (r1: 32 VGPR/446MB, r2: 40 VGPR/254MB). Natural
//      allocation (~80) -> 4 waves/SIMD, no spill; the 1-row/4096-block
//      shape already demonstrated 52% occupancy in r2.
//      - count pass: non-returning ds_add (no rtn wait);
//      - final pass: rank taken directly from atomicAdd_rtn on the
//        scanned histogram (base++ arrival, intra-bin-arbitrary order —
//        verified absmax 0.0 in rounds 1-2).
//      Last block (done-counter) computes the 3 output scalars.

#define N 4096
#define DX 512
#define DZ 64
#define NBIN 2048
#define NWRD (NBIN / 2)

typedef __attribute__((ext_vector_type(8))) short short8;
typedef __attribute__((ext_vector_type(4))) float float4v;

// qstats word layout (u32 index):
//   [0..1] rank_acc (u64)  [2..3] pd_acc (double)
//   [4] maxx [5] maxz      [6] minx [7] minz    [8] done-counter
#define ST_MAX 4
#define ST_MIN 6
#define ST_DONE 8

// ---------------- async 16B global -> LDS ----------------
__device__ __forceinline__ void async16(const void* g, void* l) {
  __builtin_amdgcn_global_load_lds(
      (const __attribute__((address_space(1))) unsigned int*)(g),
      (__attribute__((address_space(3))) unsigned int*)(l), 16, 0, 0);
}

// ---------------- prep: barrier-free wave-per-row ----------------
__global__ __launch_bounds__(256) void prep_kernel(
    const float* __restrict__ x, const float* __restrict__ z,
    __hip_bfloat16* __restrict__ xb, __hip_bfloat16* __restrict__ zb,
    float* __restrict__ nx, float* __restrict__ nz,
    unsigned* __restrict__ qstats) {
  int tid = threadIdx.x;
  if (blockIdx.x == 0 && tid < 9)
    qstats[tid] = (tid == 6 || tid == 7) ? 0xFFFFFFFFu : 0u;

  int lane = tid & 63;
  int row = (int)blockIdx.x * 4 + (tid >> 6);

  const float4* xr = (const float4*)(x + (size_t)row * DX);
  float4 a = xr[lane];
  float4 b = xr[lane + 64];
  float s = a.x * a.x + a.y * a.y + a.z * a.z + a.w * a.w +
            b.x * b.x + b.y * b.y + b.z * b.z + b.w * b.w;
#pragma unroll
  for (int d = 32; d; d >>= 1) s += __shfl_xor(s, d, 64);
  if (lane == 0) nx[row] = s;

  ushort4 pa, pb;
  pa.x = __bfloat16_as_ushort(__float2bfloat16(a.x));
  pa.y = __bfloat16_as_ushort(__float2bfloat16(a.y));
  pa.z = __bfloat16_as_ushort(__float2bfloat16(a.z));
  pa.w = __bfloat16_as_ushort(__float2bfloat16(a.w));
  pb.x = __bfloat16_as_ushort(__float2bfloat16(b.x));
  pb.y = __bfloat16_as_ushort(__float2bfloat16(b.y));
  pb.z = __bfloat16_as_ushort(__float2bfloat16(b.z));
  pb.w = __bfloat16_as_ushort(__float2bfloat16(b.w));
  ushort4* xbo = (ushort4*)(xb + (size_t)row * DX);
  xbo[lane] = pa;
  xbo[lane + 64] = pb;

  float4 c = {0.f, 0.f, 0.f, 0.f};
  if (lane < 16) c = ((const float4*)(z + (size_t)row * DZ))[lane];
  float sz = c.x * c.x + c.y * c.y + c.z * c.z + c.w * c.w;
#pragma unroll
  for (int d = 32; d; d >>= 1) sz += __shfl_xor(sz, d, 64);
  if (lane == 0) nz[row] = sz;
  if (lane < 16) {
    ushort4 pc;
    pc.x = __bfloat16_as_ushort(__float2bfloat16(c.x));
    pc.y = __bfloat16_as_ushort(__float2bfloat16(c.y));
    pc.z = __bfloat16_as_ushort(__float2bfloat16(c.z));
    pc.w = __bfloat16_as_ushort(__float2bfloat16(c.w));
    ((ushort4*)(zb + (size_t)row * DZ))[lane] = pc;
  }
}

// ------- bf16 MFMA Gram, BK=64/barrier, symmetric triangular grid --------
#define TILE 128
#define BK 64     // staged K per barrier (two 32-col sub-tiles)
#define PADW 132  // ctile row stride in u16 (66 words, 8B-aligned b64)
#define NT 32
#define NTRI 528

// smem layout (65536 B total):
//   buffer b (b=0,1) at b*32768:
//     A-half0 @0, A-half1 @8192, B-half0 @16384, B-half1 @24576 (each 8 KB,
//     [128][32] bf16 — identical bank layout to the m97-verified BK=32 tile)
//   ctile aliases smem[0..33791] after the K-loop.
//   mmx aliases smem[0..31] in the final (barrier-separated) reduce phase.

__device__ __forceinline__ void gram_tile(
    const __hip_bfloat16* __restrict__ Abf, const float* __restrict__ norms,
    unsigned short* __restrict__ distq, int K, float qscale,
    unsigned* __restrict__ qstats, int slot, int by, int bx, char* smem) {
  unsigned short* ctile = (unsigned short*)smem;
  unsigned* mmx = (unsigned*)smem;

  int tid = threadIdx.x;
  int wave = tid >> 6, lane = tid & 63;
  int wr = wave >> 1, wc = wave & 1;
  int quad = lane >> 4, l15 = lane & 15;

  int rowBase = by * TILE;
  int colBase = bx * TILE;

  float4v acc[4][4];
#pragma unroll
  for (int mi = 0; mi < 4; ++mi)
#pragma unroll
    for (int ni = 0; ni < 4; ++ni) {
      float4v zv = {0.f, 0.f, 0.f, 0.f};
      acc[mi][ni] = zv;
    }

  const char* Ab = (const char*)Abf;
  const size_t rb = (size_t)K * 2;
  int chunk0 = wave * 2, chunk1 = wave * 2 + 1;
  int rl = lane >> 2;
  int cl = (lane & 3) * 16;

  // stage BK=64 chunk (two 32-col halves) into buffer b
  auto stage = [&](int kc, int b) {
#pragma unroll
    for (int h = 0; h < 2; ++h) {
      const char* base = Ab + (size_t)(kc + h * 32) * 2 + cl;
      short* sA = (short*)(smem + b * 32768 + h * 8192);
      short* sB = (short*)(smem + b * 32768 + 16384 + h * 8192);
      async16(base + (size_t)(rowBase + chunk0 * 16 + rl) * rb,
              &sA[chunk0 * 512]);
      async16(base + (size_t)(rowBase + chunk1 * 16 + rl) * rb,
              &sA[chunk1 * 512]);
      async16(base + (size_t)(colBase + chunk0 * 16 + rl) * rb,
              &sB[chunk0 * 512]);
      async16(base + (size_t)(colBase + chunk1 * 16 + rl) * rb,
              &sB[chunk1 * 512]);
    }
  };

  stage(0, 0);
  int ib = 0;
  for (int kc = 0; kc < K; kc += BK, ib ^= 1) {
    __syncthreads();  // drains current buf's staging; prev readers done
    if (kc + BK < K) stage(kc + BK, ib ^ 1);

#pragma unroll
    for (int h = 0; h < 2; ++h) {
      const short* As = (const short*)(smem + ib * 32768 + h * 8192);
      const short* Bs = (const short*)(smem + ib * 32768 + 16384 + h * 8192);
      short8 a[4], b[4];
#pragma unroll
      for (int mi = 0; mi < 4; ++mi)
        a[mi] =
            *(const short8*)(&As[(wr * 64 + mi * 16 + l15) * 32 + quad * 8]);
#pragma unroll
      for (int ni = 0; ni < 4; ++ni)
        b[ni] =
            *(const short8*)(&Bs[(wc * 64 + ni * 16 + l15) * 32 + quad * 8]);
#pragma unroll
      for (int mi = 0; mi < 4; ++mi)
#pragma unroll
        for (int ni = 0; ni < 4; ++ni)
          acc[mi][ni] = __builtin_amdgcn_mfma_f32_16x16x32_bf16(
              a[mi], b[ni], acc[mi][ni], 0, 0, 0);
    }
  }
  __syncthreads();  // all staging reads done before ctile aliasing write

  // quantize: stage [row][col] in LDS + keep packed u64 per column
  unsigned mn = 0xFFFFu, mx = 0u;
  unsigned long long qp[4][4];
#pragma unroll
  for (int mi = 0; mi < 4; ++mi) {
#pragma unroll
    for (int ni = 0; ni < 4; ++ni) {
      int colL = wc * 64 + ni * 16 + l15;
      float ncol = norms[colBase + colL];
      unsigned long long pk = 0ull;
#pragma unroll
      for (int r = 0; r < 4; ++r) {
        int rowL = wr * 64 + mi * 16 + quad * 4 + r;
        int row = rowBase + rowL;
        float sq = norms[row] + ncol - 2.0f * acc[mi][ni][r];
        float d = sq > 0.f ? sqrtf(sq) : 0.f;
        if (row == colBase + colL) d = 0.f;
        unsigned q = (unsigned)(d * qscale);
        q = q > 65535u ? 65535u : q;
        ctile[rowL * PADW + colL] = (unsigned short)q;
        pk |= (unsigned long long)q << (16 * r);
        mx = max(mx, q);
        mn = min(mn, (row == colBase + colL) ? 0xFFFFu : q);
      }
      qp[mi][ni] = pk;
    }
  }
  __syncthreads();

  // pass A: upper tile, coalesced uint4 rows
  {
    const unsigned* cw = (const unsigned*)ctile;
    int i0 = tid >> 4, k4 = (tid & 15) * 4;
#pragma unroll
    for (int s = 0; s < 8; ++s) {
      int i = s * 16 + i0;
      int wb = i * (PADW / 2) + k4;
      uint4 v;
      v.x = cw[wb + 0];
      v.y = cw[wb + 1];
      v.z = cw[wb + 2];
      v.w = cw[wb + 3];
      *(uint4*)(distq + (size_t)(rowBase + i) * N + colBase + (tid & 15) * 8) =
          v;
    }
  }

  // pass B: mirror tile via transposed restage (off-diag only)
  if (by != bx) {
    __syncthreads();
#pragma unroll
    for (int mi = 0; mi < 4; ++mi)
#pragma unroll
      for (int ni = 0; ni < 4; ++ni) {
        int colL = wc * 64 + ni * 16 + l15;
        int rowL0 = wr * 64 + mi * 16 + quad * 4;
        *(unsigned long long*)&ctile[colL * PADW + rowL0] = qp[mi][ni];
      }
    __syncthreads();
    const unsigned* cw = (const unsigned*)ctile;
    int j0 = tid >> 4, k4 = (tid & 15) * 4;
#pragma unroll
    for (int s = 0; s < 8; ++s) {
      int j = s * 16 + j0;
      int wb = j * (PADW / 2) + k4;
      uint4 v;
      v.x = cw[wb + 0];
      v.y = cw[wb + 1];
      v.z = cw[wb + 2];
      v.w = cw[wb + 3];
      *(uint4*)(distq + (size_t)(colBase + j) * N + rowBase + (tid & 15) * 8) =
          v;
    }
  }

  // block-level min/max reduce -> 2 device atomics per tile
#pragma unroll
  for (int d = 32; d; d >>= 1) {
    mn = min(mn, (unsigned)__shfl_xor((int)mn, d, 64));
    mx = max(mx, (unsigned)__shfl_xor((int)mx, d, 64));
  }
  __syncthreads();  // ctile/pass-B reads done; mmx aliasing safe
  if (lane == 0) {
    mmx[wave] = mn;
    mmx[4 + wave] = mx;
  }
  __syncthreads();
  if (tid == 0) {
    unsigned bmn = min(min(mmx[0], mmx[1]), min(mmx[2], mmx[3]));
    unsigned bmx = max(max(mmx[4], mmx[5]), max(mmx[6], mmx[7]));
    atomicMin(&qstats[ST_MIN + slot], bmn);
    atomicMax(&qstats[ST_MAX + slot], bmx);
  }
}

__global__ __launch_bounds__(256) void gram_both_kernel(
    const __hip_bfloat16* __restrict__ xb, const __hip_bfloat16* __restrict__ zb,
    const float* __restrict__ nx, const float* __restrict__ nz,
    unsigned short* __restrict__ qx16, unsigned short* __restrict__ qz16,
    unsigned* __restrict__ qstats) {
  __shared__ alignas(16) char smem[65536];  // dbuf staging; ctile/mmx aliased

  // compact upper-triangular decode: row-major rows by=0..31, len 32-by
  int idx = (int)blockIdx.x;
  int by = (int)((65.0f - sqrtf(4225.0f - 8.0f * (float)idx)) * 0.5f);
  while (((by + 1) * (65 - (by + 1))) / 2 <= idx) ++by;
  while ((by * (65 - by)) / 2 > idx) --by;
  int bx = by + (idx - (by * (65 - by)) / 2);

  gram_tile(zb, nz, qz16, DZ, 2048.0f, qstats, 1, by, bx, smem);
  __syncthreads();
  gram_tile(xb, nx, qx16, DX, 1024.0f, qstats, 0, by, bx, smem);
}

// ---------------- counting-based per-row ranks (1 row / block) ----------
__device__ __forceinline__ int hsw(int w) { return w ^ ((w >> 5) & 31); }

__global__ __launch_bounds__(256) void rank_kernel(
    const unsigned short* __restrict__ qx,
    const unsigned short* __restrict__ qz, unsigned* __restrict__ qstats,
    float* __restrict__ out) {
  __shared__ unsigned histX[NWRD];
  __shared__ unsigned histZ[NWRD];
  __shared__ unsigned xch[32];

  unsigned long long* rank_acc = (unsigned long long*)qstats;
  double* pd_acc = (double*)(qstats + 2);

  int t = threadIdx.x, lane = t & 63, wv = t >> 6;
  int row = (int)blockIdx.x;

  float lox = (float)(int)qstats[ST_MIN + 0];
  float scx = (float)(NBIN - 1) /
              (float)(int)max(1u, qstats[ST_MAX + 0] - qstats[ST_MIN + 0]);
  float loz = (float)(int)qstats[ST_MIN + 1];
  float scz = (float)(NBIN - 1) /
              (float)(int)max(1u, qstats[ST_MAX + 1] - qstats[ST_MIN + 1]);

  const uint4* px = (const uint4*)(qx + (size_t)row * N);
  const uint4* pz = (const uint4*)(qz + (size_t)row * N);

  uint4 cxa = px[t * 2], cxb = px[t * 2 + 1];
  uint4 cza = pz[t * 2], czb = pz[t * 2 + 1];

#pragma unroll
  for (int i = 0; i < 4; ++i) {
    histX[t + 256 * i] = 0u;
    histZ[t + 256 * i] = 0u;
  }

  unsigned xw[8] = {cxa.x, cxa.y, cxa.z, cxa.w, cxb.x, cxb.y, cxb.z, cxb.w};
  unsigned zw[8] = {cza.x, cza.y, cza.z, cza.w, czb.x, czb.y, czb.z, czb.w};

  // pairdist accumulation (no LDS) fills the gap before the zeroing barrier
  float pd = 0.f;
#pragma unroll
  for (int c = 0; c < 16; ++c) {
    unsigned qxv = (xw[c >> 1] >> ((c & 1) * 16)) & 0xFFFFu;
    unsigned qzv = (zw[c >> 1] >> ((c & 1) * 16)) & 0xFFFFu;
    // dz-dx = (qz - 2*qx - 0.5)/2048
    float tv = (float)(int)qzv - 2.0f * (float)(int)qxv - 0.5f;
    pd += tv * tv;
  }
  __syncthreads();  // zeros visible to all waves

  // count pass: non-returning LDS adds (ds_add, no rtn wait)
#pragma unroll
  for (int c = 0; c < 16; ++c) {
    unsigned qxv = (xw[c >> 1] >> ((c & 1) * 16)) & 0xFFFFu;
    unsigned qzv = (zw[c >> 1] >> ((c & 1) * 16)) & 0xFFFFu;
    unsigned bx = (unsigned)(int)fminf(
        fmaxf(((float)(int)qxv - lox) * scx, 0.0f), (float)(NBIN - 1));
    unsigned bz = (unsigned)(int)fminf(
        fmaxf(((float)(int)qzv - loz) * scz, 0.0f), (float)(NBIN - 1));
    atomicAdd(&histX[hsw((int)(bx >> 1))], 1u << ((bx & 1) * 16));
    atomicAdd(&histZ[hsw((int)(bz >> 1))], 1u << ((bz & 1) * 16));
  }
  __syncthreads();

  // dual exclusive scan: waves 0-1 -> histX, waves 2-3 -> histZ
  {
    unsigned* h = (wv < 2) ? histX : histZ;
    int t2 = t & 127;
    int wb = t2 * 8;
    unsigned run = 0;
#pragma unroll
    for (int c = 0; c < 8; ++c) {
      int w = hsw(wb + c);
      unsigned v = h[w];
      unsigned lo = v & 0xFFFFu;
      h[w] = run | ((run + lo) << 16);
      run += lo + (v >> 16);
    }
    unsigned incl = run;
#pragma unroll
    for (int d = 1; d < 64; d <<= 1) {
      unsigned o = (unsigned)__shfl_up((int)incl, d, 64);
      if (lane >= d) incl += o;
    }
    if (lane == 63) xch[16 + wv] = incl;
    __syncthreads();
    unsigned base = incl - run;
    if (wv & 1) base += xch[16 + (wv - 1)];
    unsigned add = base * 0x10001u;
#pragma unroll
    for (int c = 0; c < 8; ++c) h[hsw(wb + c)] += add;
  }
  __syncthreads();

  // final pass: rank = returned base (base++ arrival within bin)
  int rsum = 0;
#pragma unroll
  for (int c = 0; c < 16; ++c) {
    unsigned qxv = (xw[c >> 1] >> ((c & 1) * 16)) & 0xFFFFu;
    unsigned qzv = (zw[c >> 1] >> ((c & 1) * 16)) & 0xFFFFu;
    unsigned bx = (unsigned)(int)fminf(
        fmaxf(((float)(int)qxv - lox) * scx, 0.0f), (float)(NBIN - 1));
    unsigned bz = (unsigned)(int)fminf(
        fmaxf(((float)(int)qzv - loz) * scz, 0.0f), (float)(NBIN - 1));
    unsigned shx = (bx & 1) * 16, shz = (bz & 1) * 16;
    int rx = (int)((atomicAdd(&histX[hsw((int)(bx >> 1))], 1u << shx) >> shx) &
                   0xFFFFu);
    int rz = (int)((atomicAdd(&histZ[hsw((int)(bz >> 1))], 1u << shz) >> shz) &
                   0xFFFFu);
    int d = rx - rz;
    rsum += d < 0 ? -d : d;
  }

  // block reduce + global atomics + last-block finalize
#pragma unroll
  for (int d = 32; d; d >>= 1) {
    rsum += __shfl_xor(rsum, d, 64);
    pd += __shfl_xor(pd, d, 64);
  }
  if (lane == 0) {
    xch[wv] = (unsigned)rsum;
    ((float*)xch)[8 + wv] = pd;
  }
  __syncthreads();
  if (t == 0) {
    unsigned long long rtot =
        (unsigned long long)xch[0] + xch[1] + xch[2] + xch[3];
    float ptot = ((float*)xch)[8] + ((float*)xch)[9] + ((float*)xch)[10] +
                 ((float*)xch)[11];
    atomicAdd(rank_acc, rtot);
    atomicAdd(pd_acc, (double)ptot);
    __threadfence();
    unsigned old = atomicAdd(&qstats[ST_DONE], 1u);
    if (old == (unsigned)gridDim.x - 1u) {
      unsigned long long rall = atomicAdd(rank_acc, 0ull);
      double pall = atomicAdd(pd_acc, 0.0);
      double inv = 1.0 / ((double)N * (double)N);
      double rank_loss = (double)rall * inv / 32.0;  // K = 32
      double pdv = pall * inv / (2048.0 * 2048.0);   // undo q scaling
      out[0] = (float)(rank_loss + 0.5 * pdv);
      out[1] = (float)rank_loss;
      out[2] = (float)pdv;
    }
  }
}

// ---------------- launch ----------------
extern "C" void kernel_launch(void* const* d_in, const int* in_sizes, int n_in,
                              void* d_out, int out_size, void* d_ws,
                              size_t ws_size, hipStream_t stream) {
  (void)in_sizes; (void)n_in; (void)out_size; (void)ws_size;
  const float* x = (const float*)d_in[0];
  const float* z = (const float*)d_in[1];
  float* out = (float*)d_out;

  char* w = (char*)d_ws;
  unsigned short* qx16 = (unsigned short*)(w);             // 32 MB
  unsigned short* qz16 = (unsigned short*)(w + 33554432);  // 32 MB
  __hip_bfloat16* xb = (__hip_bfloat16*)(w + 67108864);    // 4 MB
  __hip_bfloat16* zb = (__hip_bfloat16*)(w + 71303168);    // 0.5 MB
  float* nx = (float*)(w + 71827456);
  float* nz = (float*)(w + 71843840);
  unsigned* qstats = (unsigned*)(w + 71860224);

  prep_kernel<<<N / 4, 256, 0, stream>>>(x, z, xb, zb, nx, nz, qstats);

  gram_both_kernel<<<NTRI, 256, 0, stream>>>(xb, zb, nx, nz, qx16, qz16,
                                             qstats);

  rank_kernel<<<N, 256, 0, stream>>>(qx16, qz16, qstats, out);
}

// Round 4
// 202.193 us; speedup vs baseline: 1.9113x; 1.3611x over previous
//
#include <hip/hip_runtime.h>
#include <hip/hip_bf16.h>

// Problem: N=4096, Dx=512, Dz=64.
// out[0]=total, out[1]=rank_loss, out[2]=pairdist_loss (f32).
//
// Pipeline:
//   1. prep (barrier-free): one wave per row; float4 loads, shuffle-only
//      reductions, packed bf16 ushort4 stores; inits qstats.
//   2. gram_both: 528 symmetric triangular 128-tiles, each block does
//      z-tile (K=64) then x-tile (K=512). BK=64 PER BARRIER. LDS-staged
//      coalesced uint4 dist writes; mirror tile via LDS transpose restage.
//      q0=min(floor(d*qscale),65535), qscale 1024 (x) / 2048 (z).
//   3. rank kernel v5: round-0 structure (RPB loop, register prefetch,
//      count-pass atomic-rtn arrival capture) with RPB=2 / grid 2048.
//      SESSION LESSONS (r1-r3): natural live set ~76-84 VGPR in every
//      variant -> 4 waves/SIMD bucket (quantized at 64/128/256); forcing
//      <64 via launch_bounds spills 250-450 MB to scratch (r1/r2);
//      dropping the RPB loop+prefetch (r3, RPB=1) removes latency
//      amortization -> 163 us despite no spill. So: keep amortizing
//      structure, add block TURNOVER (8 blocks/CU supply over 4 resident)
//      to desynchronize phases across resident blocks (r0's grid==
//      capacity meant all 4 blocks convoy through the same pipe-phase;
//      VALUBusy 30%, all pipes idle at barriers together).
//      Last block (done-counter) computes the 3 output scalars.

#define N 4096
#define DX 512
#define DZ 64
#define NBIN 2048
#define NWRD (NBIN / 2)
#define RPB 2

typedef __attribute__((ext_vector_type(8))) short short8;
typedef __attribute__((ext_vector_type(4))) float float4v;

// qstats word layout (u32 index):
//   [0..1] rank_acc (u64)  [2..3] pd_acc (double)
//   [4] maxx [5] maxz      [6] minx [7] minz    [8] done-counter
#define ST_MAX 4
#define ST_MIN 6
#define ST_DONE 8

// ---------------- async 16B global -> LDS ----------------
__device__ __forceinline__ void async16(const void* g, void* l) {
  __builtin_amdgcn_global_load_lds(
      (const __attribute__((address_space(1))) unsigned int*)(g),
      (__attribute__((address_space(3))) unsigned int*)(l), 16, 0, 0);
}

// ---------------- prep: barrier-free wave-per-row ----------------
__global__ __launch_bounds__(256) void prep_kernel(
    const float* __restrict__ x, const float* __restrict__ z,
    __hip_bfloat16* __restrict__ xb, __hip_bfloat16* __restrict__ zb,
    float* __restrict__ nx, float* __restrict__ nz,
    unsigned* __restrict__ qstats) {
  int tid = threadIdx.x;
  if (blockIdx.x == 0 && tid < 9)
    qstats[tid] = (tid == 6 || tid == 7) ? 0xFFFFFFFFu : 0u;

  int lane = tid & 63;
  int row = (int)blockIdx.x * 4 + (tid >> 6);

  const float4* xr = (const float4*)(x + (size_t)row * DX);
  float4 a = xr[lane];
  float4 b = xr[lane + 64];
  float s = a.x * a.x + a.y * a.y + a.z * a.z + a.w * a.w +
            b.x * b.x + b.y * b.y + b.z * b.z + b.w * b.w;
#pragma unroll
  for (int d = 32; d; d >>= 1) s += __shfl_xor(s, d, 64);
  if (lane == 0) nx[row] = s;

  ushort4 pa, pb;
  pa.x = __bfloat16_as_ushort(__float2bfloat16(a.x));
  pa.y = __bfloat16_as_ushort(__float2bfloat16(a.y));
  pa.z = __bfloat16_as_ushort(__float2bfloat16(a.z));
  pa.w = __bfloat16_as_ushort(__float2bfloat16(a.w));
  pb.x = __bfloat16_as_ushort(__float2bfloat16(b.x));
  pb.y = __bfloat16_as_ushort(__float2bfloat16(b.y));
  pb.z = __bfloat16_as_ushort(__float2bfloat16(b.z));
  pb.w = __bfloat16_as_ushort(__float2bfloat16(b.w));
  ushort4* xbo = (ushort4*)(xb + (size_t)row * DX);
  xbo[lane] = pa;
  xbo[lane + 64] = pb;

  float4 c = {0.f, 0.f, 0.f, 0.f};
  if (lane < 16) c = ((const float4*)(z + (size_t)row * DZ))[lane];
  float sz = c.x * c.x + c.y * c.y + c.z * c.z + c.w * c.w;
#pragma unroll
  for (int d = 32; d; d >>= 1) sz += __shfl_xor(sz, d, 64);
  if (lane == 0) nz[row] = sz;
  if (lane < 16) {
    ushort4 pc;
    pc.x = __bfloat16_as_ushort(__float2bfloat16(c.x));
    pc.y = __bfloat16_as_ushort(__float2bfloat16(c.y));
    pc.z = __bfloat16_as_ushort(__float2bfloat16(c.z));
    pc.w = __bfloat16_as_ushort(__float2bfloat16(c.w));
    ((ushort4*)(zb + (size_t)row * DZ))[lane] = pc;
  }
}

// ------- bf16 MFMA Gram, BK=64/barrier, symmetric triangular grid --------
#define TILE 128
#define BK 64     // staged K per barrier (two 32-col sub-tiles)
#define PADW 132  // ctile row stride in u16 (66 words, 8B-aligned b64)
#define NT 32
#define NTRI 528

// smem layout (65536 B total):
//   buffer b (b=0,1) at b*32768:
//     A-half0 @0, A-half1 @8192, B-half0 @16384, B-half1 @24576 (each 8 KB,
//     [128][32] bf16 — identical bank layout to the m97-verified BK=32 tile)
//   ctile aliases smem[0..33791] after the K-loop.
//   mmx aliases smem[0..31] in the final (barrier-separated) reduce phase.

__device__ __forceinline__ void gram_tile(
    const __hip_bfloat16* __restrict__ Abf, const float* __restrict__ norms,
    unsigned short* __restrict__ distq, int K, float qscale,
    unsigned* __restrict__ qstats, int slot, int by, int bx, char* smem) {
  unsigned short* ctile = (unsigned short*)smem;
  unsigned* mmx = (unsigned*)smem;

  int tid = threadIdx.x;
  int wave = tid >> 6, lane = tid & 63;
  int wr = wave >> 1, wc = wave & 1;
  int quad = lane >> 4, l15 = lane & 15;

  int rowBase = by * TILE;
  int colBase = bx * TILE;

  float4v acc[4][4];
#pragma unroll
  for (int mi = 0; mi < 4; ++mi)
#pragma unroll
    for (int ni = 0; ni < 4; ++ni) {
      float4v zv = {0.f, 0.f, 0.f, 0.f};
      acc[mi][ni] = zv;
    }

  const char* Ab = (const char*)Abf;
  const size_t rb = (size_t)K * 2;
  int chunk0 = wave * 2, chunk1 = wave * 2 + 1;
  int rl = lane >> 2;
  int cl = (lane & 3) * 16;

  // stage BK=64 chunk (two 32-col halves) into buffer b
  auto stage = [&](int kc, int b) {
#pragma unroll
    for (int h = 0; h < 2; ++h) {
      const char* base = Ab + (size_t)(kc + h * 32) * 2 + cl;
      short* sA = (short*)(smem + b * 32768 + h * 8192);
      short* sB = (short*)(smem + b * 32768 + 16384 + h * 8192);
      async16(base + (size_t)(rowBase + chunk0 * 16 + rl) * rb,
              &sA[chunk0 * 512]);
      async16(base + (size_t)(rowBase + chunk1 * 16 + rl) * rb,
              &sA[chunk1 * 512]);
      async16(base + (size_t)(colBase + chunk0 * 16 + rl) * rb,
              &sB[chunk0 * 512]);
      async16(base + (size_t)(colBase + chunk1 * 16 + rl) * rb,
              &sB[chunk1 * 512]);
    }
  };

  stage(0, 0);
  int ib = 0;
  for (int kc = 0; kc < K; kc += BK, ib ^= 1) {
    __syncthreads();  // drains current buf's staging; prev readers done
    if (kc + BK < K) stage(kc + BK, ib ^ 1);

#pragma unroll
    for (int h = 0; h < 2; ++h) {
      const short* As = (const short*)(smem + ib * 32768 + h * 8192);
      const short* Bs = (const short*)(smem + ib * 32768 + 16384 + h * 8192);
      short8 a[4], b[4];
#pragma unroll
      for (int mi = 0; mi < 4; ++mi)
        a[mi] =
            *(const short8*)(&As[(wr * 64 + mi * 16 + l15) * 32 + quad * 8]);
#pragma unroll
      for (int ni = 0; ni < 4; ++ni)
        b[ni] =
            *(const short8*)(&Bs[(wc * 64 + ni * 16 + l15) * 32 + quad * 8]);
#pragma unroll
      for (int mi = 0; mi < 4; ++mi)
#pragma unroll
        for (int ni = 0; ni < 4; ++ni)
          acc[mi][ni] = __builtin_amdgcn_mfma_f32_16x16x32_bf16(
              a[mi], b[ni], acc[mi][ni], 0, 0, 0);
    }
  }
  __syncthreads();  // all staging reads done before ctile aliasing write

  // quantize: stage [row][col] in LDS + keep packed u64 per column
  unsigned mn = 0xFFFFu, mx = 0u;
  unsigned long long qp[4][4];
#pragma unroll
  for (int mi = 0; mi < 4; ++mi) {
#pragma unroll
    for (int ni = 0; ni < 4; ++ni) {
      int colL = wc * 64 + ni * 16 + l15;
      float ncol = norms[colBase + colL];
      unsigned long long pk = 0ull;
#pragma unroll
      for (int r = 0; r < 4; ++r) {
        int rowL = wr * 64 + mi * 16 + quad * 4 + r;
        int row = rowBase + rowL;
        float sq = norms[row] + ncol - 2.0f * acc[mi][ni][r];
        float d = sq > 0.f ? sqrtf(sq) : 0.f;
        if (row == colBase + colL) d = 0.f;
        unsigned q = (unsigned)(d * qscale);
        q = q > 65535u ? 65535u : q;
        ctile[rowL * PADW + colL] = (unsigned short)q;
        pk |= (unsigned long long)q << (16 * r);
        mx = max(mx, q);
        mn = min(mn, (row == colBase + colL) ? 0xFFFFu : q);
      }
      qp[mi][ni] = pk;
    }
  }
  __syncthreads();

  // pass A: upper tile, coalesced uint4 rows
  {
    const unsigned* cw = (const unsigned*)ctile;
    int i0 = tid >> 4, k4 = (tid & 15) * 4;
#pragma unroll
    for (int s = 0; s < 8; ++s) {
      int i = s * 16 + i0;
      int wb = i * (PADW / 2) + k4;
      uint4 v;
      v.x = cw[wb + 0];
      v.y = cw[wb + 1];
      v.z = cw[wb + 2];
      v.w = cw[wb + 3];
      *(uint4*)(distq + (size_t)(rowBase + i) * N + colBase + (tid & 15) * 8) =
          v;
    }
  }

  // pass B: mirror tile via transposed restage (off-diag only)
  if (by != bx) {
    __syncthreads();
#pragma unroll
    for (int mi = 0; mi < 4; ++mi)
#pragma unroll
      for (int ni = 0; ni < 4; ++ni) {
        int colL = wc * 64 + ni * 16 + l15;
        int rowL0 = wr * 64 + mi * 16 + quad * 4;
        *(unsigned long long*)&ctile[colL * PADW + rowL0] = qp[mi][ni];
      }
    __syncthreads();
    const unsigned* cw = (const unsigned*)ctile;
    int j0 = tid >> 4, k4 = (tid & 15) * 4;
#pragma unroll
    for (int s = 0; s < 8; ++s) {
      int j = s * 16 + j0;
      int wb = j * (PADW / 2) + k4;
      uint4 v;
      v.x = cw[wb + 0];
      v.y = cw[wb + 1];
      v.z = cw[wb + 2];
      v.w = cw[wb + 3];
      *(uint4*)(distq + (size_t)(colBase + j) * N + rowBase + (tid & 15) * 8) =
          v;
    }
  }

  // block-level min/max reduce -> 2 device atomics per tile
#pragma unroll
  for (int d = 32; d; d >>= 1) {
    mn = min(mn, (unsigned)__shfl_xor((int)mn, d, 64));
    mx = max(mx, (unsigned)__shfl_xor((int)mx, d, 64));
  }
  __syncthreads();  // ctile/pass-B reads done; mmx aliasing safe
  if (lane == 0) {
    mmx[wave] = mn;
    mmx[4 + wave] = mx;
  }
  __syncthreads();
  if (tid == 0) {
    unsigned bmn = min(min(mmx[0], mmx[1]), min(mmx[2], mmx[3]));
    unsigned bmx = max(max(mmx[4], mmx[5]), max(mmx[6], mmx[7]));
    atomicMin(&qstats[ST_MIN + slot], bmn);
    atomicMax(&qstats[ST_MAX + slot], bmx);
  }
}

__global__ __launch_bounds__(256) void gram_both_kernel(
    const __hip_bfloat16* __restrict__ xb, const __hip_bfloat16* __restrict__ zb,
    const float* __restrict__ nx, const float* __restrict__ nz,
    unsigned short* __restrict__ qx16, unsigned short* __restrict__ qz16,
    unsigned* __restrict__ qstats) {
  __shared__ alignas(16) char smem[65536];  // dbuf staging; ctile/mmx aliased

  // compact upper-triangular decode: row-major rows by=0..31, len 32-by
  int idx = (int)blockIdx.x;
  int by = (int)((65.0f - sqrtf(4225.0f - 8.0f * (float)idx)) * 0.5f);
  while (((by + 1) * (65 - (by + 1))) / 2 <= idx) ++by;
  while ((by * (65 - by)) / 2 > idx) --by;
  int bx = by + (idx - (by * (65 - by)) / 2);

  gram_tile(zb, nz, qz16, DZ, 2048.0f, qstats, 1, by, bx, smem);
  __syncthreads();
  gram_tile(xb, nx, qx16, DX, 1024.0f, qstats, 0, by, bx, smem);
}

// ---------------- counting-based per-row ranks (RPB rows / block) --------
__device__ __forceinline__ int hsw(int w) { return w ^ ((w >> 5) & 31); }

__global__ __launch_bounds__(256) void rank_kernel(
    const unsigned short* __restrict__ qx,
    const unsigned short* __restrict__ qz, unsigned* __restrict__ qstats,
    float* __restrict__ out) {
  __shared__ unsigned histX[NWRD];
  __shared__ unsigned histZ[NWRD];
  __shared__ unsigned xch[32];

  unsigned long long* rank_acc = (unsigned long long*)qstats;
  double* pd_acc = (double*)(qstats + 2);

  int t = threadIdx.x, lane = t & 63, wv = t >> 6;
  int row0 = (int)blockIdx.x * RPB;

  float lox = (float)(int)qstats[ST_MIN + 0];
  float scx = (float)(NBIN - 1) /
              (float)(int)max(1u, qstats[ST_MAX + 0] - qstats[ST_MIN + 0]);
  float loz = (float)(int)qstats[ST_MIN + 1];
  float scz = (float)(NBIN - 1) /
              (float)(int)max(1u, qstats[ST_MAX + 1] - qstats[ST_MIN + 1]);

  const uint4* px = (const uint4*)(qx + (size_t)row0 * N);
  const uint4* pz = (const uint4*)(qz + (size_t)row0 * N);

  uint4 cxa = px[t * 2], cxb = px[t * 2 + 1];
  uint4 cza = pz[t * 2], czb = pz[t * 2 + 1];

  float pd = 0.f;
  int rsum = 0;

#pragma unroll 1
  for (int r = 0; r < RPB; ++r) {
#pragma unroll
    for (int i = 0; i < 4; ++i) {
      histX[t + 256 * i] = 0u;
      histZ[t + 256 * i] = 0u;
    }
    uint4 nxa = cxa, nxb = cxb, nza = cza, nzb = czb;
    if (r + 1 < RPB) {
      const uint4* npx = px + (size_t)(r + 1) * (N / 8);
      const uint4* npz = pz + (size_t)(r + 1) * (N / 8);
      nxa = npx[t * 2];
      nxb = npx[t * 2 + 1];
      nza = npz[t * 2];
      nzb = npz[t * 2 + 1];
    }

    unsigned xw[8] = {cxa.x, cxa.y, cxa.z, cxa.w, cxb.x, cxb.y, cxb.z, cxb.w};
    unsigned zw[8] = {cza.x, cza.y, cza.z, cza.w, czb.x, czb.y, czb.z, czb.w};

#pragma unroll
    for (int c = 0; c < 16; ++c) {
      unsigned qxv = (xw[c >> 1] >> ((c & 1) * 16)) & 0xFFFFu;
      unsigned qzv = (zw[c >> 1] >> ((c & 1) * 16)) & 0xFFFFu;
      // dz-dx = (qz - 2*qx - 0.5)/2048
      float tv = (float)(int)qzv - 2.0f * (float)(int)qxv - 0.5f;
      pd += tv * tv;
    }
    __syncthreads();

    unsigned oxp[8], ozp[8];
#pragma unroll
    for (int c = 0; c < 16; ++c) {
      unsigned qxv = (xw[c >> 1] >> ((c & 1) * 16)) & 0xFFFFu;
      unsigned qzv = (zw[c >> 1] >> ((c & 1) * 16)) & 0xFFFFu;
      unsigned bx = (unsigned)(int)fminf(
          fmaxf(((float)(int)qxv - lox) * scx, 0.0f), (float)(NBIN - 1));
      unsigned bz = (unsigned)(int)fminf(
          fmaxf(((float)(int)qzv - loz) * scz, 0.0f), (float)(NBIN - 1));
      unsigned shx = (bx & 1) * 16, shz = (bz & 1) * 16;
      unsigned ox =
          (atomicAdd(&histX[hsw((int)(bx >> 1))], 1u << shx) >> shx) & 0xFFFFu;
      unsigned oz =
          (atomicAdd(&histZ[hsw((int)(bz >> 1))], 1u << shz) >> shz) & 0xFFFFu;
      if (c & 1) {
        oxp[c >> 1] |= ox << 16;
        ozp[c >> 1] |= oz << 16;
      } else {
        oxp[c >> 1] = ox;
        ozp[c >> 1] = oz;
      }
    }
    __syncthreads();

    {
      unsigned* h = (wv < 2) ? histX : histZ;
      int t2 = t & 127;
      int wb = t2 * 8;
      unsigned run = 0;
#pragma unroll
      for (int c = 0; c < 8; ++c) {
        int w = hsw(wb + c);
        unsigned v = h[w];
        unsigned lo = v & 0xFFFFu;
        h[w] = run | ((run + lo) << 16);
        run += lo + (v >> 16);
      }
      unsigned incl = run;
#pragma unroll
      for (int d = 1; d < 64; d <<= 1) {
        unsigned o = (unsigned)__shfl_up((int)incl, d, 64);
        if (lane >= d) incl += o;
      }
      if (lane == 63) xch[16 + wv] = incl;
      __syncthreads();
      unsigned base = incl - run;
      if (wv & 1) base += xch[16 + (wv - 1)];
      unsigned add = base * 0x10001u;
#pragma unroll
      for (int c = 0; c < 8; ++c) h[hsw(wb + c)] += add;
    }
    __syncthreads();

#pragma unroll
    for (int c = 0; c < 16; ++c) {
      unsigned qxv = (xw[c >> 1] >> ((c & 1) * 16)) & 0xFFFFu;
      unsigned qzv = (zw[c >> 1] >> ((c & 1) * 16)) & 0xFFFFu;
      unsigned bx = (unsigned)(int)fminf(
          fmaxf(((float)(int)qxv - lox) * scx, 0.0f), (float)(NBIN - 1));
      unsigned bz = (unsigned)(int)fminf(
          fmaxf(((float)(int)qzv - loz) * scz, 0.0f), (float)(NBIN - 1));
      unsigned shx = (bx & 1) * 16, shz = (bz & 1) * 16;
      unsigned basex = (histX[hsw((int)(bx >> 1))] >> shx) & 0xFFFFu;
      unsigned basez = (histZ[hsw((int)(bz >> 1))] >> shz) & 0xFFFFu;
      int rx = (int)(basex + ((oxp[c >> 1] >> ((c & 1) * 16)) & 0xFFFFu));
      int rz = (int)(basez + ((ozp[c >> 1] >> ((c & 1) * 16)) & 0xFFFFu));
      int d = rx - rz;
      rsum += d < 0 ? -d : d;
    }
    __syncthreads();

    cxa = nxa;
    cxb = nxb;
    cza = nza;
    czb = nzb;
  }

  // block reduce + global atomics + last-block finalize
#pragma unroll
  for (int d = 32; d; d >>= 1) {
    rsum += __shfl_xor(rsum, d, 64);
    pd += __shfl_xor(pd, d, 64);
  }
  if (lane == 0) {
    xch[wv] = (unsigned)rsum;
    ((float*)xch)[8 + wv] = pd;
  }
  __syncthreads();
  if (t == 0) {
    unsigned long long rtot =
        (unsigned long long)xch[0] + xch[1] + xch[2] + xch[3];
    float ptot = ((float*)xch)[8] + ((float*)xch)[9] + ((float*)xch)[10] +
                 ((float*)xch)[11];
    atomicAdd(rank_acc, rtot);
    atomicAdd(pd_acc, (double)ptot);
    __threadfence();
    unsigned old = atomicAdd(&qstats[ST_DONE], 1u);
    if (old == (unsigned)gridDim.x - 1u) {
      unsigned long long rall = atomicAdd(rank_acc, 0ull);
      double pall = atomicAdd(pd_acc, 0.0);
      double inv = 1.0 / ((double)N * (double)N);
      double rank_loss = (double)rall * inv / 32.0;  // K = 32
      double pdv = pall * inv / (2048.0 * 2048.0);   // undo q scaling
      out[0] = (float)(rank_loss + 0.5 * pdv);
      out[1] = (float)rank_loss;
      out[2] = (float)pdv;
    }
  }
}

// ---------------- launch ----------------
extern "C" void kernel_launch(void* const* d_in, const int* in_sizes, int n_in,
                              void* d_out, int out_size, void* d_ws,
                              size_t ws_size, hipStream_t stream) {
  (void)in_sizes; (void)n_in; (void)out_size; (void)ws_size;
  const float* x = (const float*)d_in[0];
  const float* z = (const float*)d_in[1];
  float* out = (float*)d_out;

  char* w = (char*)d_ws;
  unsigned short* qx16 = (unsigned short*)(w);             // 32 MB
  unsigned short* qz16 = (unsigned short*)(w + 33554432);  // 32 MB
  __hip_bfloat16* xb = (__hip_bfloat16*)(w + 67108864);    // 4 MB
  __hip_bfloat16* zb = (__hip_bfloat16*)(w + 71303168);    // 0.5 MB
  float* nx = (float*)(w + 71827456);
  float* nz = (float*)(w + 71843840);
  unsigned* qstats = (unsigned*)(w + 71860224);

  prep_kernel<<<N / 4, 256, 0, stream>>>(x, z, xb, zb, nx, nz, qstats);

  gram_both_kernel<<<NTRI, 256, 0, stream>>>(xb, zb, nx, nz, qx16, qz16,
                                             qstats);

  rank_kernel<<<N / RPB, 256, 0, stream>>>(qx16, qz16, qstats, out);
}

// Round 6
// 177.220 us; speedup vs baseline: 2.1806x; 1.1409x over previous
//
#include <hip/hip_runtime.h>
#include <hip/hip_bf16.h>
#include <hip/hip_cooperative_groups.h>

namespace cg = cooperative_groups;

// Problem: N=4096, Dx=512, Dz=64.
// out[0]=total, out[1]=rank_loss, out[2]=pairdist_loss (f32).
//
// ROUND-6: guarded single cooperative kernel (CGRID=256, 1 block/CU —
// r5 LESSON: coop validation uses API occupancy with sharedMemPerMP=64KB,
// so a 64KB-LDS kernel validates at 1 block/CU and grid 512 is REJECTED;
// r5's launch silently failed, outputs stayed 0). kernel_launch checks
// occupancy*CUs >= CGRID and the launch's return code; on any failure it
// falls back to the verbatim r0 three-kernel path (proven 168 us,
// absmax 0.0) — the experiment cannot fail the bench.
//
// Fused phases (internals verbatim from verified r0/r4 kernels):
//   1. prep: 16 rows/block, barrier-free.
//   2. gram, balanced over 256 workers: x-tiles (K=512, heavy) bid,
//      bid+256, plus 512+bid for bid<16; those 16 blocks skip z entirely;
//      z-tiles (K=64, ~1/9 cost) spread over blocks 16..255 (j=bid-16:
//      j, j+240, j<48: j+480). Critical path ~2.67 x-tiles vs 3 naive.
//   3. rank: RPB=16 rows/block, count-pass rtn arrival capture + dual
//      scan + final-pass base add (intra-bin-arbitrary, absmax 0.0 in
//      r0-r4). Last block (done-counter) computes the 3 outputs.
// Cross-phase visibility: cg::grid.sync(); scale words re-read via
// atomicAdd(.,0).

#define N 4096
#define DX 512
#define DZ 64
#define NBIN 2048
#define NWRD (NBIN / 2)
#define RPB 4    // fallback rank kernel (r0 config)
#define RPBF 16  // fused rank phase
#define CGRID 256

typedef __attribute__((ext_vector_type(8))) short short8;
typedef __attribute__((ext_vector_type(4))) float float4v;

// qstats word layout (u32 index):
//   [0..1] rank_acc (u64)  [2..3] pd_acc (double)
//   [4] maxx [5] maxz      [6] minx [7] minz    [8] done-counter
#define ST_MAX 4
#define ST_MIN 6
#define ST_DONE 8

// ---------------- async 16B global -> LDS ----------------
__device__ __forceinline__ void async16(const void* g, void* l) {
  __builtin_amdgcn_global_load_lds(
      (const __attribute__((address_space(1))) unsigned int*)(g),
      (__attribute__((address_space(3))) unsigned int*)(l), 16, 0, 0);
}

// ---------------- prep body (4 rows per call) ----------------
__device__ __forceinline__ void prep_rows(
    const float* __restrict__ x, const float* __restrict__ z,
    __hip_bfloat16* __restrict__ xb, __hip_bfloat16* __restrict__ zb,
    float* __restrict__ nx, float* __restrict__ nz, int row, int lane) {
  const float4* xr = (const float4*)(x + (size_t)row * DX);
  float4 a = xr[lane];
  float4 b = xr[lane + 64];
  float s = a.x * a.x + a.y * a.y + a.z * a.z + a.w * a.w +
            b.x * b.x + b.y * b.y + b.z * b.z + b.w * b.w;
#pragma unroll
  for (int d = 32; d; d >>= 1) s += __shfl_xor(s, d, 64);
  if (lane == 0) nx[row] = s;

  ushort4 pa, pb;
  pa.x = __bfloat16_as_ushort(__float2bfloat16(a.x));
  pa.y = __bfloat16_as_ushort(__float2bfloat16(a.y));
  pa.z = __bfloat16_as_ushort(__float2bfloat16(a.z));
  pa.w = __bfloat16_as_ushort(__float2bfloat16(a.w));
  pb.x = __bfloat16_as_ushort(__float2bfloat16(b.x));
  pb.y = __bfloat16_as_ushort(__float2bfloat16(b.y));
  pb.z = __bfloat16_as_ushort(__float2bfloat16(b.z));
  pb.w = __bfloat16_as_ushort(__float2bfloat16(b.w));
  ushort4* xbo = (ushort4*)(xb + (size_t)row * DX);
  xbo[lane] = pa;
  xbo[lane + 64] = pb;

  float4 c = {0.f, 0.f, 0.f, 0.f};
  if (lane < 16) c = ((const float4*)(z + (size_t)row * DZ))[lane];
  float sz = c.x * c.x + c.y * c.y + c.z * c.z + c.w * c.w;
#pragma unroll
  for (int d = 32; d; d >>= 1) sz += __shfl_xor(sz, d, 64);
  if (lane == 0) nz[row] = sz;
  if (lane < 16) {
    ushort4 pc;
    pc.x = __bfloat16_as_ushort(__float2bfloat16(c.x));
    pc.y = __bfloat16_as_ushort(__float2bfloat16(c.y));
    pc.z = __bfloat16_as_ushort(__float2bfloat16(c.z));
    pc.w = __bfloat16_as_ushort(__float2bfloat16(c.w));
    ((ushort4*)(zb + (size_t)row * DZ))[lane] = pc;
  }
}

// ---------------- fallback prep kernel (r0 verbatim behavior) -----------
__global__ __launch_bounds__(256) void prep_kernel(
    const float* __restrict__ x, const float* __restrict__ z,
    __hip_bfloat16* __restrict__ xb, __hip_bfloat16* __restrict__ zb,
    float* __restrict__ nx, float* __restrict__ nz,
    unsigned* __restrict__ qstats) {
  int tid = threadIdx.x;
  if (blockIdx.x == 0 && tid < 9)
    qstats[tid] = (tid == 6 || tid == 7) ? 0xFFFFFFFFu : 0u;
  prep_rows(x, z, xb, zb, nx, nz, (int)blockIdx.x * 4 + (tid >> 6), tid & 63);
}

// ------- bf16 MFMA Gram, BK=64/barrier, symmetric triangular grid --------
#define TILE 128
#define BK 64     // staged K per barrier (two 32-col sub-tiles)
#define PADW 132  // ctile row stride in u16 (66 words, 8B-aligned b64)
#define NTRI 528

// smem layout (65536 B total):
//   buffer b (b=0,1) at b*32768:
//     A-half0 @0, A-half1 @8192, B-half0 @16384, B-half1 @24576 (each 8 KB,
//     [128][32] bf16 — m97-verified layout)
//   ctile aliases smem[0..33791] after the K-loop.
//   mmx aliases smem[0..31] in the final (barrier-separated) reduce phase.
//   rank phase aliases histX @0, histZ @4096, xch @8192.

__device__ __forceinline__ void gram_tile(
    const __hip_bfloat16* __restrict__ Abf, const float* __restrict__ norms,
    unsigned short* __restrict__ distq, int K, float qscale,
    unsigned* __restrict__ qstats, int slot, int by, int bx, char* smem) {
  unsigned short* ctile = (unsigned short*)smem;
  unsigned* mmx = (unsigned*)smem;

  int tid = threadIdx.x;
  int wave = tid >> 6, lane = tid & 63;
  int wr = wave >> 1, wc = wave & 1;
  int quad = lane >> 4, l15 = lane & 15;

  int rowBase = by * TILE;
  int colBase = bx * TILE;

  float4v acc[4][4];
#pragma unroll
  for (int mi = 0; mi < 4; ++mi)
#pragma unroll
    for (int ni = 0; ni < 4; ++ni) {
      float4v zv = {0.f, 0.f, 0.f, 0.f};
      acc[mi][ni] = zv;
    }

  const char* Ab = (const char*)Abf;
  const size_t rb = (size_t)K * 2;
  int chunk0 = wave * 2, chunk1 = wave * 2 + 1;
  int rl = lane >> 2;
  int cl = (lane & 3) * 16;

  auto stage = [&](int kc, int b) {
#pragma unroll
    for (int h = 0; h < 2; ++h) {
      const char* base = Ab + (size_t)(kc + h * 32) * 2 + cl;
      short* sA = (short*)(smem + b * 32768 + h * 8192);
      short* sB = (short*)(smem + b * 32768 + 16384 + h * 8192);
      async16(base + (size_t)(rowBase + chunk0 * 16 + rl) * rb,
              &sA[chunk0 * 512]);
      async16(base + (size_t)(rowBase + chunk1 * 16 + rl) * rb,
              &sA[chunk1 * 512]);
      async16(base + (size_t)(colBase + chunk0 * 16 + rl) * rb,
              &sB[chunk0 * 512]);
      async16(base + (size_t)(colBase + chunk1 * 16 + rl) * rb,
              &sB[chunk1 * 512]);
    }
  };

  stage(0, 0);
  int ib = 0;
  for (int kc = 0; kc < K; kc += BK, ib ^= 1) {
    __syncthreads();  // drains current buf's staging; prev readers done
    if (kc + BK < K) stage(kc + BK, ib ^ 1);

#pragma unroll
    for (int h = 0; h < 2; ++h) {
      const short* As = (const short*)(smem + ib * 32768 + h * 8192);
      const short* Bs = (const short*)(smem + ib * 32768 + 16384 + h * 8192);
      short8 a[4], b[4];
#pragma unroll
      for (int mi = 0; mi < 4; ++mi)
        a[mi] =
            *(const short8*)(&As[(wr * 64 + mi * 16 + l15) * 32 + quad * 8]);
#pragma unroll
      for (int ni = 0; ni < 4; ++ni)
        b[ni] =
            *(const short8*)(&Bs[(wc * 64 + ni * 16 + l15) * 32 + quad * 8]);
#pragma unroll
      for (int mi = 0; mi < 4; ++mi)
#pragma unroll
        for (int ni = 0; ni < 4; ++ni)
          acc[mi][ni] = __builtin_amdgcn_mfma_f32_16x16x32_bf16(
              a[mi], b[ni], acc[mi][ni], 0, 0, 0);
    }
  }
  __syncthreads();  // all staging reads done before ctile aliasing write

  // quantize: stage [row][col] in LDS + keep packed u64 per column
  unsigned mn = 0xFFFFu, mx = 0u;
  unsigned long long qp[4][4];
#pragma unroll
  for (int mi = 0; mi < 4; ++mi) {
#pragma unroll
    for (int ni = 0; ni < 4; ++ni) {
      int colL = wc * 64 + ni * 16 + l15;
      float ncol = norms[colBase + colL];
      unsigned long long pk = 0ull;
#pragma unroll
      for (int r = 0; r < 4; ++r) {
        int rowL = wr * 64 + mi * 16 + quad * 4 + r;
        int row = rowBase + rowL;
        float sq = norms[row] + ncol - 2.0f * acc[mi][ni][r];
        float d = sq > 0.f ? sqrtf(sq) : 0.f;
        if (row == colBase + colL) d = 0.f;
        unsigned q = (unsigned)(d * qscale);
        q = q > 65535u ? 65535u : q;
        ctile[rowL * PADW + colL] = (unsigned short)q;
        pk |= (unsigned long long)q << (16 * r);
        mx = max(mx, q);
        mn = min(mn, (row == colBase + colL) ? 0xFFFFu : q);
      }
      qp[mi][ni] = pk;
    }
  }
  __syncthreads();

  // pass A: upper tile, coalesced uint4 rows
  {
    const unsigned* cw = (const unsigned*)ctile;
    int i0 = tid >> 4, k4 = (tid & 15) * 4;
#pragma unroll
    for (int s = 0; s < 8; ++s) {
      int i = s * 16 + i0;
      int wb = i * (PADW / 2) + k4;
      uint4 v;
      v.x = cw[wb + 0];
      v.y = cw[wb + 1];
      v.z = cw[wb + 2];
      v.w = cw[wb + 3];
      *(uint4*)(distq + (size_t)(rowBase + i) * N + colBase + (tid & 15) * 8) =
          v;
    }
  }

  // pass B: mirror tile via transposed restage (off-diag only)
  if (by != bx) {
    __syncthreads();
#pragma unroll
    for (int mi = 0; mi < 4; ++mi)
#pragma unroll
      for (int ni = 0; ni < 4; ++ni) {
        int colL = wc * 64 + ni * 16 + l15;
        int rowL0 = wr * 64 + mi * 16 + quad * 4;
        *(unsigned long long*)&ctile[colL * PADW + rowL0] = qp[mi][ni];
      }
    __syncthreads();
    const unsigned* cw = (const unsigned*)ctile;
    int j0 = tid >> 4, k4 = (tid & 15) * 4;
#pragma unroll
    for (int s = 0; s < 8; ++s) {
      int j = s * 16 + j0;
      int wb = j * (PADW / 2) + k4;
      uint4 v;
      v.x = cw[wb + 0];
      v.y = cw[wb + 1];
      v.z = cw[wb + 2];
      v.w = cw[wb + 3];
      *(uint4*)(distq + (size_t)(colBase + j) * N + rowBase + (tid & 15) * 8) =
          v;
    }
  }

  // block-level min/max reduce -> 2 device atomics per tile
#pragma unroll
  for (int d = 32; d; d >>= 1) {
    mn = min(mn, (unsigned)__shfl_xor((int)mn, d, 64));
    mx = max(mx, (unsigned)__shfl_xor((int)mx, d, 64));
  }
  __syncthreads();  // ctile/pass-B reads done; mmx aliasing safe
  if (lane == 0) {
    mmx[wave] = mn;
    mmx[4 + wave] = mx;
  }
  __syncthreads();
  if (tid == 0) {
    unsigned bmn = min(min(mmx[0], mmx[1]), min(mmx[2], mmx[3]));
    unsigned bmx = max(max(mmx[4], mmx[5]), max(mmx[6], mmx[7]));
    atomicMin(&qstats[ST_MIN + slot], bmn);
    atomicMax(&qstats[ST_MAX + slot], bmx);
  }
}

// triangular decode: row-major rows by=0..31, len 32-by
__device__ __forceinline__ void tri_decode(int idx, int& by, int& bx) {
  by = (int)((65.0f - sqrtf(4225.0f - 8.0f * (float)idx)) * 0.5f);
  while (((by + 1) * (65 - (by + 1))) / 2 <= idx) ++by;
  while ((by * (65 - by)) / 2 > idx) --by;
  bx = by + (idx - (by * (65 - by)) / 2);
}

// ---------------- fallback gram kernel (r0 verbatim) ----------------
__global__ __launch_bounds__(256) void gram_both_kernel(
    const __hip_bfloat16* __restrict__ xb, const __hip_bfloat16* __restrict__ zb,
    const float* __restrict__ nx, const float* __restrict__ nz,
    unsigned short* __restrict__ qx16, unsigned short* __restrict__ qz16,
    unsigned* __restrict__ qstats) {
  __shared__ alignas(16) char smem[65536];
  int by, bx;
  tri_decode((int)blockIdx.x, by, bx);
  gram_tile(zb, nz, qz16, DZ, 2048.0f, qstats, 1, by, bx, smem);
  __syncthreads();
  gram_tile(xb, nx, qx16, DX, 1024.0f, qstats, 0, by, bx, smem);
}

// ---------------- histogram word swizzle ----------------
__device__ __forceinline__ int hsw(int w) { return w ^ ((w >> 5) & 31); }

// ---------------- rank body: one row, using LDS hist buffers ----------
// Returns via rsum/pd accumulators. Caller supplies current-row data in
// xw/zw and handles prefetch.
template <typename XCH>
__device__ __forceinline__ void rank_row(
    const unsigned* xw, const unsigned* zw, unsigned* histX, unsigned* histZ,
    XCH xch, float lox, float scx, float loz, float scz, int tid, int lane,
    int wv, float& pd, int& rsum) {
#pragma unroll
  for (int c = 0; c < 16; ++c) {
    unsigned qxv = (xw[c >> 1] >> ((c & 1) * 16)) & 0xFFFFu;
    unsigned qzv = (zw[c >> 1] >> ((c & 1) * 16)) & 0xFFFFu;
    // dz-dx = (qz - 2*qx - 0.5)/2048
    float tv = (float)(int)qzv - 2.0f * (float)(int)qxv - 0.5f;
    pd += tv * tv;
  }
  __syncthreads();

  unsigned oxp[8], ozp[8];
#pragma unroll
  for (int c = 0; c < 16; ++c) {
    unsigned qxv = (xw[c >> 1] >> ((c & 1) * 16)) & 0xFFFFu;
    unsigned qzv = (zw[c >> 1] >> ((c & 1) * 16)) & 0xFFFFu;
    unsigned bx = (unsigned)(int)fminf(
        fmaxf(((float)(int)qxv - lox) * scx, 0.0f), (float)(NBIN - 1));
    unsigned bz = (unsigned)(int)fminf(
        fmaxf(((float)(int)qzv - loz) * scz, 0.0f), (float)(NBIN - 1));
    unsigned shx = (bx & 1) * 16, shz = (bz & 1) * 16;
    unsigned ox =
        (atomicAdd(&histX[hsw((int)(bx >> 1))], 1u << shx) >> shx) & 0xFFFFu;
    unsigned oz =
        (atomicAdd(&histZ[hsw((int)(bz >> 1))], 1u << shz) >> shz) & 0xFFFFu;
    if (c & 1) {
      oxp[c >> 1] |= ox << 16;
      ozp[c >> 1] |= oz << 16;
    } else {
      oxp[c >> 1] = ox;
      ozp[c >> 1] = oz;
    }
  }
  __syncthreads();

  {
    unsigned* h = (wv < 2) ? histX : histZ;
    int t2 = tid & 127;
    int wb = t2 * 8;
    unsigned run = 0;
#pragma unroll
    for (int c = 0; c < 8; ++c) {
      int w = hsw(wb + c);
      unsigned v = h[w];
      unsigned lo = v & 0xFFFFu;
      h[w] = run | ((run + lo) << 16);
      run += lo + (v >> 16);
    }
    unsigned incl = run;
#pragma unroll
    for (int d = 1; d < 64; d <<= 1) {
      unsigned o = (unsigned)__shfl_up((int)incl, d, 64);
      if (lane >= d) incl += o;
    }
    if (lane == 63) xch[16 + wv] = incl;
    __syncthreads();
    unsigned base = incl - run;
    if (wv & 1) base += xch[16 + (wv - 1)];
    unsigned add = base * 0x10001u;
#pragma unroll
    for (int c = 0; c < 8; ++c) h[hsw(wb + c)] += add;
  }
  __syncthreads();

#pragma unroll
  for (int c = 0; c < 16; ++c) {
    unsigned qxv = (xw[c >> 1] >> ((c & 1) * 16)) & 0xFFFFu;
    unsigned qzv = (zw[c >> 1] >> ((c & 1) * 16)) & 0xFFFFu;
    unsigned bx = (unsigned)(int)fminf(
        fmaxf(((float)(int)qxv - lox) * scx, 0.0f), (float)(NBIN - 1));
    unsigned bz = (unsigned)(int)fminf(
        fmaxf(((float)(int)qzv - loz) * scz, 0.0f), (float)(NBIN - 1));
    unsigned shx = (bx & 1) * 16, shz = (bz & 1) * 16;
    unsigned basex = (histX[hsw((int)(bx >> 1))] >> shx) & 0xFFFFu;
    unsigned basez = (histZ[hsw((int)(bz >> 1))] >> shz) & 0xFFFFu;
    int rx = (int)(basex + ((oxp[c >> 1] >> ((c & 1) * 16)) & 0xFFFFu));
    int rz = (int)(basez + ((ozp[c >> 1] >> ((c & 1) * 16)) & 0xFFFFu));
    int d = rx - rz;
    rsum += d < 0 ? -d : d;
  }
  __syncthreads();
}

// ---------------- shared finalize (block reduce + atomics) --------------
__device__ __forceinline__ void rank_finalize(
    unsigned* xch, unsigned* qstats, float* out, int tid, int lane, int wv,
    int rsum, float pd, unsigned nblocks) {
  unsigned long long* rank_acc = (unsigned long long*)qstats;
  double* pd_acc = (double*)(qstats + 2);
#pragma unroll
  for (int d = 32; d; d >>= 1) {
    rsum += __shfl_xor(rsum, d, 64);
    pd += __shfl_xor(pd, d, 64);
  }
  if (lane == 0) {
    xch[wv] = (unsigned)rsum;
    ((float*)xch)[8 + wv] = pd;
  }
  __syncthreads();
  if (tid == 0) {
    unsigned long long rtot =
        (unsigned long long)xch[0] + xch[1] + xch[2] + xch[3];
    float ptot = ((float*)xch)[8] + ((float*)xch)[9] + ((float*)xch)[10] +
                 ((float*)xch)[11];
    atomicAdd(rank_acc, rtot);
    atomicAdd(pd_acc, (double)ptot);
    __threadfence();
    unsigned old = atomicAdd(&qstats[ST_DONE], 1u);
    if (old == nblocks - 1u) {
      unsigned long long rall = atomicAdd(rank_acc, 0ull);
      double pall = atomicAdd(pd_acc, 0.0);
      double inv = 1.0 / ((double)N * (double)N);
      double rank_loss = (double)rall * inv / 32.0;  // K = 32
      double pdv = pall * inv / (2048.0 * 2048.0);   // undo q scaling
      out[0] = (float)(rank_loss + 0.5 * pdv);
      out[1] = (float)rank_loss;
      out[2] = (float)pdv;
    }
  }
}

// ---------------- fallback rank kernel (r0 verbatim, RPB=4) -------------
__global__ __launch_bounds__(256) void rank_kernel(
    const unsigned short* __restrict__ qx,
    const unsigned short* __restrict__ qz, unsigned* __restrict__ qstats,
    float* __restrict__ out) {
  __shared__ unsigned histX[NWRD];
  __shared__ unsigned histZ[NWRD];
  __shared__ unsigned xch[32];

  int tid = threadIdx.x, lane = tid & 63, wv = tid >> 6;
  int row0 = (int)blockIdx.x * RPB;

  float lox = (float)(int)qstats[ST_MIN + 0];
  float scx = (float)(NBIN - 1) /
              (float)(int)max(1u, qstats[ST_MAX + 0] - qstats[ST_MIN + 0]);
  float loz = (float)(int)qstats[ST_MIN + 1];
  float scz = (float)(NBIN - 1) /
              (float)(int)max(1u, qstats[ST_MAX + 1] - qstats[ST_MIN + 1]);

  const uint4* px = (const uint4*)(qx + (size_t)row0 * N);
  const uint4* pz = (const uint4*)(qz + (size_t)row0 * N);

  uint4 cxa = px[tid * 2], cxb = px[tid * 2 + 1];
  uint4 cza = pz[tid * 2], czb = pz[tid * 2 + 1];

  float pd = 0.f;
  int rsum = 0;

#pragma unroll 1
  for (int r = 0; r < RPB; ++r) {
#pragma unroll
    for (int i = 0; i < 4; ++i) {
      histX[tid + 256 * i] = 0u;
      histZ[tid + 256 * i] = 0u;
    }
    uint4 nxa = cxa, nxb = cxb, nza = cza, nzb = czb;
    if (r + 1 < RPB) {
      const uint4* npx = px + (size_t)(r + 1) * (N / 8);
      const uint4* npz = pz + (size_t)(r + 1) * (N / 8);
      nxa = npx[tid * 2];
      nxb = npx[tid * 2 + 1];
      nza = npz[tid * 2];
      nzb = npz[tid * 2 + 1];
    }
    unsigned xw[8] = {cxa.x, cxa.y, cxa.z, cxa.w, cxb.x, cxb.y, cxb.z, cxb.w};
    unsigned zw[8] = {cza.x, cza.y, cza.z, cza.w, czb.x, czb.y, czb.z, czb.w};
    rank_row(xw, zw, histX, histZ, xch, lox, scx, loz, scz, tid, lane, wv, pd,
             rsum);
    cxa = nxa;
    cxb = nxb;
    cza = nza;
    czb = nzb;
  }
  rank_finalize(xch, qstats, out, tid, lane, wv, rsum, pd,
                (unsigned)gridDim.x);
}

// ==================== fused cooperative kernel ====================
__global__ __launch_bounds__(256) void fused_kernel(
    const float* __restrict__ x, const float* __restrict__ z,
    __hip_bfloat16* __restrict__ xb, __hip_bfloat16* __restrict__ zb,
    float* __restrict__ nx, float* __restrict__ nz,
    unsigned short* __restrict__ qx, unsigned short* __restrict__ qz,
    unsigned* __restrict__ qstats, float* __restrict__ out) {
  __shared__ alignas(16) char smem[65536];
  cg::grid_group grid = cg::this_grid();

  int tid = threadIdx.x;
  int bid = (int)blockIdx.x;
  int lane = tid & 63, wv = tid >> 6;

  // ---------------- phase 1: prep (16 rows/block) ----------------------
  if (bid == 0 && tid < 9)
    qstats[tid] = (tid == 6 || tid == 7) ? 0xFFFFFFFFu : 0u;

#pragma unroll
  for (int rr = 0; rr < 4; ++rr)
    prep_rows(x, z, xb, zb, nx, nz, bid * 16 + rr * 4 + wv, lane);

  grid.sync();  // prep outputs + qstats init visible device-wide

  // ---------------- phase 2: gram, balanced z/x assignment --------------
  // x-tiles (heavy): all blocks do bid, bid+256; blocks 0..15 also 512+bid
  // and are excused from z; z-tiles spread over blocks 16..255.
  if (bid >= 16) {
    int j = bid - 16;
    int nzt = (j < 48) ? 3 : 2;
    for (int q = 0; q < nzt; ++q) {
      int by, bx;
      tri_decode(j + q * 240, by, bx);
      gram_tile(zb, nz, qz, DZ, 2048.0f, qstats, 1, by, bx, smem);
      __syncthreads();
    }
  }
  {
    int nxt = (bid < 16) ? 3 : 2;
    for (int q = 0; q < nxt; ++q) {
      int by, bx;
      tri_decode(bid + q * 256, by, bx);
      gram_tile(xb, nx, qx, DX, 1024.0f, qstats, 0, by, bx, smem);
      __syncthreads();
    }
  }

  grid.sync();  // qx/qz + min/max stats visible device-wide

  // ---------------- phase 3: rank (RPBF=16 rows/block) ------------------
  unsigned* histX = (unsigned*)smem;
  unsigned* histZ = (unsigned*)(smem + 4096);
  unsigned* xch = (unsigned*)(smem + 8192);

  // coherent scale fetch (atomic rtn read -> LDS stash -> broadcast)
  if (tid < 4) xch[tid] = atomicAdd(&qstats[ST_MAX + tid], 0u);
  __syncthreads();
  unsigned maxx_ = xch[0], maxz_ = xch[1], minx_ = xch[2], minz_ = xch[3];
  __syncthreads();
  float lox = (float)(int)minx_;
  float scx = (float)(NBIN - 1) / (float)(int)max(1u, maxx_ - minx_);
  float loz = (float)(int)minz_;
  float scz = (float)(NBIN - 1) / (float)(int)max(1u, maxz_ - minz_);

  int row0 = bid * RPBF;
  const uint4* px = (const uint4*)(qx + (size_t)row0 * N);
  const uint4* pz = (const uint4*)(qz + (size_t)row0 * N);

  uint4 cxa = px[tid * 2], cxb = px[tid * 2 + 1];
  uint4 cza = pz[tid * 2], czb = pz[tid * 2 + 1];

  float pd = 0.f;
  int rsum = 0;

#pragma unroll 1
  for (int r = 0; r < RPBF; ++r) {
#pragma unroll
    for (int i = 0; i < 4; ++i) {
      histX[tid + 256 * i] = 0u;
      histZ[tid + 256 * i] = 0u;
    }
    uint4 nxa = cxa, nxb = cxb, nza = cza, nzb = czb;
    if (r + 1 < RPBF) {
      const uint4* npx = px + (size_t)(r + 1) * (N / 8);
      const uint4* npz = pz + (size_t)(r + 1) * (N / 8);
      nxa = npx[tid * 2];
      nxb = npx[tid * 2 + 1];
      nza = npz[tid * 2];
      nzb = npz[tid * 2 + 1];
    }
    unsigned xw[8] = {cxa.x, cxa.y, cxa.z, cxa.w, cxb.x, cxb.y, cxb.z, cxb.w};
    unsigned zw[8] = {cza.x, cza.y, cza.z, cza.w, czb.x, czb.y, czb.z, czb.w};
    rank_row(xw, zw, histX, histZ, xch, lox, scx, loz, scz, tid, lane, wv, pd,
             rsum);
    cxa = nxa;
    cxb = nxb;
    cza = nza;
    czb = nzb;
  }
  rank_finalize(xch, qstats, out, tid, lane, wv, rsum, pd, (unsigned)CGRID);
}

// ---------------- launch ----------------
extern "C" void kernel_launch(void* const* d_in, const int* in_sizes, int n_in,
                              void* d_out, int out_size, void* d_ws,
                              size_t ws_size, hipStream_t stream) {
  (void)in_sizes; (void)n_in; (void)out_size; (void)ws_size;
  const float* x = (const float*)d_in[0];
  const float* z = (const float*)d_in[1];
  float* out = (float*)d_out;

  char* w = (char*)d_ws;
  unsigned short* qx16 = (unsigned short*)(w);             // 32 MB
  unsigned short* qz16 = (unsigned short*)(w + 33554432);  // 32 MB
  __hip_bfloat16* xb = (__hip_bfloat16*)(w + 67108864);    // 4 MB
  __hip_bfloat16* zb = (__hip_bfloat16*)(w + 71303168);    // 0.5 MB
  float* nx = (float*)(w + 71827456);
  float* nz = (float*)(w + 71843840);
  unsigned* qstats = (unsigned*)(w + 71860224);

  // one-time cooperative-capacity check (host-side queries; capture-safe)
  static int coop_ok = -1;
  if (coop_ok < 0) {
    int dev = 0, ncu = 0, nb = 0;
    (void)hipGetDevice(&dev);
    (void)hipDeviceGetAttribute(&ncu, hipDeviceAttributeMultiprocessorCount,
                                dev);
    (void)hipOccupancyMaxActiveBlocksPerMultiprocessor(&nb, fused_kernel, 256,
                                                       0);
    coop_ok = (nb >= 1 && (long)nb * (long)ncu >= (long)CGRID) ? 1 : 0;
  }

  if (coop_ok) {
    void* args[] = {(void*)&x,      (void*)&z,    (void*)&xb,   (void*)&zb,
                    (void*)&nx,     (void*)&nz,   (void*)&qx16, (void*)&qz16,
                    (void*)&qstats, (void*)&out};
    hipError_t e = hipLaunchCooperativeKernel((const void*)fused_kernel,
                                              dim3(CGRID), dim3(256), args, 0,
                                              stream);
    if (e == hipSuccess) return;
    coop_ok = 0;  // permanent fallback from here on
  }

  // fallback: proven r0 three-kernel path (168 us, absmax 0.0)
  prep_kernel<<<N / 4, 256, 0, stream>>>(x, z, xb, zb, nx, nz, qstats);
  gram_both_kernel<<<NTRI, 256, 0, stream>>>(xb, zb, nx, nz, qx16, qz16,
                                             qstats);
  rank_kernel<<<N / RPB, 256, 0, stream>>>(qx16, qz16, qstats, out);
}

// Round 7
// 169.569 us; speedup vs baseline: 2.2790x; 1.0451x over previous
//
#include <hip/hip_runtime.h>
#include <hip/hip_bf16.h>
#include <hip/hip_cooperative_groups.h>

namespace cg = cooperative_groups;

// Problem: N=4096, Dx=512, Dz=64.
// out[0]=total, out[1]=rank_loss, out[2]=pairdist_loss (f32).
//
// ROUND-7: fused coop kernel at 512 THREADS/BLOCK, CGRID=256.
// r6 lesson: fusion saves ~33 us of launch overhead (measured: 1 launch
// = ~17 us, 3 launches = ~50 us) but at 256 thr/block the fused phases
// ran at 4 waves/CU (Occ 11%) vs r0's 8 (gram) / 16 (rank) -> dispatch
// 160 us vs ~115 us phase-sum. Fix: 512 thr/block = 8 waves/CU at an
// unchanged 1 block/CU (coop validator uses API sharedMemPerMP=64KB).
//   - gram512: verified tile re-mapped to 8 waves (2x4 grid, 64x32 per
//     wave, acc[4][2], stage chunk=wave). Same LDS layout/banks.
//   - rank: two independent 256-thread TEAMS per block, each running the
//     VERBATIM r0 rank_row on its own 8 rows with its own hist pair
//     (16 KB of LDS). Teams overlap each other's barrier drains.
//   - prep: 16 rows/block via 8 waves.
// Guarded launch + verbatim r0 3-kernel fallback retained.

#define N 4096
#define DX 512
#define DZ 64
#define NBIN 2048
#define NWRD (NBIN / 2)
#define RPB 4   // fallback rank kernel (r0 config)
#define CGRID 256
#define TPB 512

typedef __attribute__((ext_vector_type(8))) short short8;
typedef __attribute__((ext_vector_type(4))) float float4v;

// qstats word layout (u32 index):
//   [0..1] rank_acc (u64)  [2..3] pd_acc (double)
//   [4] maxx [5] maxz      [6] minx [7] minz    [8] done-counter
#define ST_MAX 4
#define ST_MIN 6
#define ST_DONE 8

// ---------------- async 16B global -> LDS ----------------
__device__ __forceinline__ void async16(const void* g, void* l) {
  __builtin_amdgcn_global_load_lds(
      (const __attribute__((address_space(1))) unsigned int*)(g),
      (__attribute__((address_space(3))) unsigned int*)(l), 16, 0, 0);
}

// ---------------- prep body (one row per wave) ----------------
__device__ __forceinline__ void prep_rows(
    const float* __restrict__ x, const float* __restrict__ z,
    __hip_bfloat16* __restrict__ xb, __hip_bfloat16* __restrict__ zb,
    float* __restrict__ nx, float* __restrict__ nz, int row, int lane) {
  const float4* xr = (const float4*)(x + (size_t)row * DX);
  float4 a = xr[lane];
  float4 b = xr[lane + 64];
  float s = a.x * a.x + a.y * a.y + a.z * a.z + a.w * a.w +
            b.x * b.x + b.y * b.y + b.z * b.z + b.w * b.w;
#pragma unroll
  for (int d = 32; d; d >>= 1) s += __shfl_xor(s, d, 64);
  if (lane == 0) nx[row] = s;

  ushort4 pa, pb;
  pa.x = __bfloat16_as_ushort(__float2bfloat16(a.x));
  pa.y = __bfloat16_as_ushort(__float2bfloat16(a.y));
  pa.z = __bfloat16_as_ushort(__float2bfloat16(a.z));
  pa.w = __bfloat16_as_ushort(__float2bfloat16(a.w));
  pb.x = __bfloat16_as_ushort(__float2bfloat16(b.x));
  pb.y = __bfloat16_as_ushort(__float2bfloat16(b.y));
  pb.z = __bfloat16_as_ushort(__float2bfloat16(b.z));
  pb.w = __bfloat16_as_ushort(__float2bfloat16(b.w));
  ushort4* xbo = (ushort4*)(xb + (size_t)row * DX);
  xbo[lane] = pa;
  xbo[lane + 64] = pb;

  float4 c = {0.f, 0.f, 0.f, 0.f};
  if (lane < 16) c = ((const float4*)(z + (size_t)row * DZ))[lane];
  float sz = c.x * c.x + c.y * c.y + c.z * c.z + c.w * c.w;
#pragma unroll
  for (int d = 32; d; d >>= 1) sz += __shfl_xor(sz, d, 64);
  if (lane == 0) nz[row] = sz;
  if (lane < 16) {
    ushort4 pc;
    pc.x = __bfloat16_as_ushort(__float2bfloat16(c.x));
    pc.y = __bfloat16_as_ushort(__float2bfloat16(c.y));
    pc.z = __bfloat16_as_ushort(__float2bfloat16(c.z));
    pc.w = __bfloat16_as_ushort(__float2bfloat16(c.w));
    ((ushort4*)(zb + (size_t)row * DZ))[lane] = pc;
  }
}

// ---------------- fallback prep kernel (r0 verbatim behavior) -----------
__global__ __launch_bounds__(256) void prep_kernel(
    const float* __restrict__ x, const float* __restrict__ z,
    __hip_bfloat16* __restrict__ xb, __hip_bfloat16* __restrict__ zb,
    float* __restrict__ nx, float* __restrict__ nz,
    unsigned* __restrict__ qstats) {
  int tid = threadIdx.x;
  if (blockIdx.x == 0 && tid < 9)
    qstats[tid] = (tid == 6 || tid == 7) ? 0xFFFFFFFFu : 0u;
  prep_rows(x, z, xb, zb, nx, nz, (int)blockIdx.x * 4 + (tid >> 6), tid & 63);
}

// ------- bf16 MFMA Gram, BK=64/barrier --------
#define TILE 128
#define BK 64     // staged K per barrier (two 32-col sub-tiles)
#define PADW 132  // ctile row stride in u16 (66 words, 8B-aligned b64)
#define NTRI 528

// ---------------- 256-thread gram tile (r0 verbatim, for fallback) ------
__device__ __forceinline__ void gram_tile(
    const __hip_bfloat16* __restrict__ Abf, const float* __restrict__ norms,
    unsigned short* __restrict__ distq, int K, float qscale,
    unsigned* __restrict__ qstats, int slot, int by, int bx, char* smem) {
  unsigned short* ctile = (unsigned short*)smem;
  unsigned* mmx = (unsigned*)smem;

  int tid = threadIdx.x;
  int wave = tid >> 6, lane = tid & 63;
  int wr = wave >> 1, wc = wave & 1;
  int quad = lane >> 4, l15 = lane & 15;

  int rowBase = by * TILE;
  int colBase = bx * TILE;

  float4v acc[4][4];
#pragma unroll
  for (int mi = 0; mi < 4; ++mi)
#pragma unroll
    for (int ni = 0; ni < 4; ++ni) {
      float4v zv = {0.f, 0.f, 0.f, 0.f};
      acc[mi][ni] = zv;
    }

  const char* Ab = (const char*)Abf;
  const size_t rb = (size_t)K * 2;
  int chunk0 = wave * 2, chunk1 = wave * 2 + 1;
  int rl = lane >> 2;
  int cl = (lane & 3) * 16;

  auto stage = [&](int kc, int b) {
#pragma unroll
    for (int h = 0; h < 2; ++h) {
      const char* base = Ab + (size_t)(kc + h * 32) * 2 + cl;
      short* sA = (short*)(smem + b * 32768 + h * 8192);
      short* sB = (short*)(smem + b * 32768 + 16384 + h * 8192);
      async16(base + (size_t)(rowBase + chunk0 * 16 + rl) * rb,
              &sA[chunk0 * 512]);
      async16(base + (size_t)(rowBase + chunk1 * 16 + rl) * rb,
              &sA[chunk1 * 512]);
      async16(base + (size_t)(colBase + chunk0 * 16 + rl) * rb,
              &sB[chunk0 * 512]);
      async16(base + (size_t)(colBase + chunk1 * 16 + rl) * rb,
              &sB[chunk1 * 512]);
    }
  };

  stage(0, 0);
  int ib = 0;
  for (int kc = 0; kc < K; kc += BK, ib ^= 1) {
    __syncthreads();
    if (kc + BK < K) stage(kc + BK, ib ^ 1);

#pragma unroll
    for (int h = 0; h < 2; ++h) {
      const short* As = (const short*)(smem + ib * 32768 + h * 8192);
      const short* Bs = (const short*)(smem + ib * 32768 + 16384 + h * 8192);
      short8 a[4], b[4];
#pragma unroll
      for (int mi = 0; mi < 4; ++mi)
        a[mi] =
            *(const short8*)(&As[(wr * 64 + mi * 16 + l15) * 32 + quad * 8]);
#pragma unroll
      for (int ni = 0; ni < 4; ++ni)
        b[ni] =
            *(const short8*)(&Bs[(wc * 64 + ni * 16 + l15) * 32 + quad * 8]);
#pragma unroll
      for (int mi = 0; mi < 4; ++mi)
#pragma unroll
        for (int ni = 0; ni < 4; ++ni)
          acc[mi][ni] = __builtin_amdgcn_mfma_f32_16x16x32_bf16(
              a[mi], b[ni], acc[mi][ni], 0, 0, 0);
    }
  }
  __syncthreads();

  unsigned mn = 0xFFFFu, mx = 0u;
  unsigned long long qp[4][4];
#pragma unroll
  for (int mi = 0; mi < 4; ++mi) {
#pragma unroll
    for (int ni = 0; ni < 4; ++ni) {
      int colL = wc * 64 + ni * 16 + l15;
      float ncol = norms[colBase + colL];
      unsigned long long pk = 0ull;
#pragma unroll
      for (int r = 0; r < 4; ++r) {
        int rowL = wr * 64 + mi * 16 + quad * 4 + r;
        int row = rowBase + rowL;
        float sq = norms[row] + ncol - 2.0f * acc[mi][ni][r];
        float d = sq > 0.f ? sqrtf(sq) : 0.f;
        if (row == colBase + colL) d = 0.f;
        unsigned q = (unsigned)(d * qscale);
        q = q > 65535u ? 65535u : q;
        ctile[rowL * PADW + colL] = (unsigned short)q;
        pk |= (unsigned long long)q << (16 * r);
        mx = max(mx, q);
        mn = min(mn, (row == colBase + colL) ? 0xFFFFu : q);
      }
      qp[mi][ni] = pk;
    }
  }
  __syncthreads();

  {
    const unsigned* cw = (const unsigned*)ctile;
    int i0 = tid >> 4, k4 = (tid & 15) * 4;
#pragma unroll
    for (int s = 0; s < 8; ++s) {
      int i = s * 16 + i0;
      int wb = i * (PADW / 2) + k4;
      uint4 v;
      v.x = cw[wb + 0];
      v.y = cw[wb + 1];
      v.z = cw[wb + 2];
      v.w = cw[wb + 3];
      *(uint4*)(distq + (size_t)(rowBase + i) * N + colBase + (tid & 15) * 8) =
          v;
    }
  }

  if (by != bx) {
    __syncthreads();
#pragma unroll
    for (int mi = 0; mi < 4; ++mi)
#pragma unroll
      for (int ni = 0; ni < 4; ++ni) {
        int colL = wc * 64 + ni * 16 + l15;
        int rowL0 = wr * 64 + mi * 16 + quad * 4;
        *(unsigned long long*)&ctile[colL * PADW + rowL0] = qp[mi][ni];
      }
    __syncthreads();
    const unsigned* cw = (const unsigned*)ctile;
    int j0 = tid >> 4, k4 = (tid & 15) * 4;
#pragma unroll
    for (int s = 0; s < 8; ++s) {
      int j = s * 16 + j0;
      int wb = j * (PADW / 2) + k4;
      uint4 v;
      v.x = cw[wb + 0];
      v.y = cw[wb + 1];
      v.z = cw[wb + 2];
      v.w = cw[wb + 3];
      *(uint4*)(distq + (size_t)(colBase + j) * N + rowBase + (tid & 15) * 8) =
          v;
    }
  }

#pragma unroll
  for (int d = 32; d; d >>= 1) {
    mn = min(mn, (unsigned)__shfl_xor((int)mn, d, 64));
    mx = max(mx, (unsigned)__shfl_xor((int)mx, d, 64));
  }
  __syncthreads();
  if (lane == 0) {
    mmx[wave] = mn;
    mmx[4 + wave] = mx;
  }
  __syncthreads();
  if (tid == 0) {
    unsigned bmn = min(min(mmx[0], mmx[1]), min(mmx[2], mmx[3]));
    unsigned bmx = max(max(mmx[4], mmx[5]), max(mmx[6], mmx[7]));
    atomicMin(&qstats[ST_MIN + slot], bmn);
    atomicMax(&qstats[ST_MAX + slot], bmx);
  }
}

// ---------------- 512-thread gram tile (fused path) ----------------
// 8 waves, grid 2x4: wave covers rows wr*64+mi*16 (mi 0..3) x cols
// wc*32+ni*16 (ni 0..1). Stage: chunk = wave (8 chunks of 16 rows).
__device__ __forceinline__ void gram_tile512(
    const __hip_bfloat16* __restrict__ Abf, const float* __restrict__ norms,
    unsigned short* __restrict__ distq, int K, float qscale,
    unsigned* __restrict__ qstats, int slot, int by, int bx, char* smem) {
  unsigned short* ctile = (unsigned short*)smem;
  unsigned* mmx = (unsigned*)smem;

  int tid = threadIdx.x;  // 0..511
  int wave = tid >> 6, lane = tid & 63;
  int wr = wave >> 2, wc = wave & 3;
  int quad = lane >> 4, l15 = lane & 15;

  int rowBase = by * TILE;
  int colBase = bx * TILE;

  float4v acc[4][2];
#pragma unroll
  for (int mi = 0; mi < 4; ++mi)
#pragma unroll
    for (int ni = 0; ni < 2; ++ni) {
      float4v zv = {0.f, 0.f, 0.f, 0.f};
      acc[mi][ni] = zv;
    }

  const char* Ab = (const char*)Abf;
  const size_t rb = (size_t)K * 2;
  int rl = lane >> 2;
  int cl = (lane & 3) * 16;

  auto stage = [&](int kc, int b) {
#pragma unroll
    for (int h = 0; h < 2; ++h) {
      const char* base = Ab + (size_t)(kc + h * 32) * 2 + cl;
      short* sA = (short*)(smem + b * 32768 + h * 8192);
      short* sB = (short*)(smem + b * 32768 + 16384 + h * 8192);
      async16(base + (size_t)(rowBase + wave * 16 + rl) * rb,
              &sA[wave * 512]);
      async16(base + (size_t)(colBase + wave * 16 + rl) * rb,
              &sB[wave * 512]);
    }
  };

  stage(0, 0);
  int ib = 0;
  for (int kc = 0; kc < K; kc += BK, ib ^= 1) {
    __syncthreads();
    if (kc + BK < K) stage(kc + BK, ib ^ 1);

#pragma unroll
    for (int h = 0; h < 2; ++h) {
      const short* As = (const short*)(smem + ib * 32768 + h * 8192);
      const short* Bs = (const short*)(smem + ib * 32768 + 16384 + h * 8192);
      short8 a[4], b[2];
#pragma unroll
      for (int mi = 0; mi < 4; ++mi)
        a[mi] =
            *(const short8*)(&As[(wr * 64 + mi * 16 + l15) * 32 + quad * 8]);
#pragma unroll
      for (int ni = 0; ni < 2; ++ni)
        b[ni] =
            *(const short8*)(&Bs[(wc * 32 + ni * 16 + l15) * 32 + quad * 8]);
#pragma unroll
      for (int mi = 0; mi < 4; ++mi)
#pragma unroll
        for (int ni = 0; ni < 2; ++ni)
          acc[mi][ni] = __builtin_amdgcn_mfma_f32_16x16x32_bf16(
              a[mi], b[ni], acc[mi][ni], 0, 0, 0);
    }
  }
  __syncthreads();  // all staging reads done before ctile aliasing write

  unsigned mn = 0xFFFFu, mx = 0u;
  unsigned long long qp[4][2];
#pragma unroll
  for (int mi = 0; mi < 4; ++mi) {
#pragma unroll
    for (int ni = 0; ni < 2; ++ni) {
      int colL = wc * 32 + ni * 16 + l15;
      float ncol = norms[colBase + colL];
      unsigned long long pk = 0ull;
#pragma unroll
      for (int r = 0; r < 4; ++r) {
        int rowL = wr * 64 + mi * 16 + quad * 4 + r;
        int row = rowBase + rowL;
        float sq = norms[row] + ncol - 2.0f * acc[mi][ni][r];
        float d = sq > 0.f ? sqrtf(sq) : 0.f;
        if (row == colBase + colL) d = 0.f;
        unsigned q = (unsigned)(d * qscale);
        q = q > 65535u ? 65535u : q;
        ctile[rowL * PADW + colL] = (unsigned short)q;
        pk |= (unsigned long long)q << (16 * r);
        mx = max(mx, q);
        mn = min(mn, (row == colBase + colL) ? 0xFFFFu : q);
      }
      qp[mi][ni] = pk;
    }
  }
  __syncthreads();

  // pass A: 512 threads, 32 rows per iter, 4 iters
  {
    const unsigned* cw = (const unsigned*)ctile;
    int i0 = tid >> 4, k4 = (tid & 15) * 4;
#pragma unroll
    for (int s = 0; s < 4; ++s) {
      int i = s * 32 + i0;
      int wb = i * (PADW / 2) + k4;
      uint4 v;
      v.x = cw[wb + 0];
      v.y = cw[wb + 1];
      v.z = cw[wb + 2];
      v.w = cw[wb + 3];
      *(uint4*)(distq + (size_t)(rowBase + i) * N + colBase + (tid & 15) * 8) =
          v;
    }
  }

  // pass B: mirror tile via transposed restage (off-diag only)
  if (by != bx) {
    __syncthreads();
#pragma unroll
    for (int mi = 0; mi < 4; ++mi)
#pragma unroll
      for (int ni = 0; ni < 2; ++ni) {
        int colL = wc * 32 + ni * 16 + l15;
        int rowL0 = wr * 64 + mi * 16 + quad * 4;
        *(unsigned long long*)&ctile[colL * PADW + rowL0] = qp[mi][ni];
      }
    __syncthreads();
    const unsigned* cw = (const unsigned*)ctile;
    int j0 = tid >> 4, k4 = (tid & 15) * 4;
#pragma unroll
    for (int s = 0; s < 4; ++s) {
      int j = s * 32 + j0;
      int wb = j * (PADW / 2) + k4;
      uint4 v;
      v.x = cw[wb + 0];
      v.y = cw[wb + 1];
      v.z = cw[wb + 2];
      v.w = cw[wb + 3];
      *(uint4*)(distq + (size_t)(colBase + j) * N + rowBase + (tid & 15) * 8) =
          v;
    }
  }

  // block min/max reduce -> 2 device atomics per tile
#pragma unroll
  for (int d = 32; d; d >>= 1) {
    mn = min(mn, (unsigned)__shfl_xor((int)mn, d, 64));
    mx = max(mx, (unsigned)__shfl_xor((int)mx, d, 64));
  }
  __syncthreads();  // ctile/pass reads done; mmx aliasing safe
  if (lane == 0) {
    mmx[wave] = mn;
    mmx[8 + wave] = mx;
  }
  __syncthreads();
  if (tid == 0) {
    unsigned bmn = mmx[0], bmx = mmx[8];
#pragma unroll
    for (int k = 1; k < 8; ++k) {
      bmn = min(bmn, mmx[k]);
      bmx = max(bmx, mmx[8 + k]);
    }
    atomicMin(&qstats[ST_MIN + slot], bmn);
    atomicMax(&qstats[ST_MAX + slot], bmx);
  }
}

// triangular decode: row-major rows by=0..31, len 32-by
__device__ __forceinline__ void tri_decode(int idx, int& by, int& bx) {
  by = (int)((65.0f - sqrtf(4225.0f - 8.0f * (float)idx)) * 0.5f);
  while (((by + 1) * (65 - (by + 1))) / 2 <= idx) ++by;
  while ((by * (65 - by)) / 2 > idx) --by;
  bx = by + (idx - (by * (65 - by)) / 2);
}

// ---------------- fallback gram kernel (r0 verbatim) ----------------
__global__ __launch_bounds__(256) void gram_both_kernel(
    const __hip_bfloat16* __restrict__ xb, const __hip_bfloat16* __restrict__ zb,
    const float* __restrict__ nx, const float* __restrict__ nz,
    unsigned short* __restrict__ qx16, unsigned short* __restrict__ qz16,
    unsigned* __restrict__ qstats) {
  __shared__ alignas(16) char smem[65536];
  int by, bx;
  tri_decode((int)blockIdx.x, by, bx);
  gram_tile(zb, nz, qz16, DZ, 2048.0f, qstats, 1, by, bx, smem);
  __syncthreads();
  gram_tile(xb, nx, qx16, DX, 1024.0f, qstats, 0, by, bx, smem);
}

// ---------------- histogram word swizzle ----------------
__device__ __forceinline__ int hsw(int w) { return w ^ ((w >> 5) & 31); }

// ---------------- rank body: one row on a 256-thread team --------------
// tid/lane/wv are TEAM-LOCAL (0..255 / 0..63 / 0..3); hist/xch team-local.
// __syncthreads() is block-wide: all teams must call in lockstep.
__device__ __forceinline__ void rank_row(
    const unsigned* xw, const unsigned* zw, unsigned* histX, unsigned* histZ,
    unsigned* xch, float lox, float scx, float loz, float scz, int tid,
    int lane, int wv, float& pd, int& rsum) {
#pragma unroll
  for (int c = 0; c < 16; ++c) {
    unsigned qxv = (xw[c >> 1] >> ((c & 1) * 16)) & 0xFFFFu;
    unsigned qzv = (zw[c >> 1] >> ((c & 1) * 16)) & 0xFFFFu;
    // dz-dx = (qz - 2*qx - 0.5)/2048
    float tv = (float)(int)qzv - 2.0f * (float)(int)qxv - 0.5f;
    pd += tv * tv;
  }
  __syncthreads();

  unsigned oxp[8], ozp[8];
#pragma unroll
  for (int c = 0; c < 16; ++c) {
    unsigned qxv = (xw[c >> 1] >> ((c & 1) * 16)) & 0xFFFFu;
    unsigned qzv = (zw[c >> 1] >> ((c & 1) * 16)) & 0xFFFFu;
    unsigned bx = (unsigned)(int)fminf(
        fmaxf(((float)(int)qxv - lox) * scx, 0.0f), (float)(NBIN - 1));
    unsigned bz = (unsigned)(int)fminf(
        fmaxf(((float)(int)qzv - loz) * scz, 0.0f), (float)(NBIN - 1));
    unsigned shx = (bx & 1) * 16, shz = (bz & 1) * 16;
    unsigned ox =
        (atomicAdd(&histX[hsw((int)(bx >> 1))], 1u << shx) >> shx) & 0xFFFFu;
    unsigned oz =
        (atomicAdd(&histZ[hsw((int)(bz >> 1))], 1u << shz) >> shz) & 0xFFFFu;
    if (c & 1) {
      oxp[c >> 1] |= ox << 16;
      ozp[c >> 1] |= oz << 16;
    } else {
      oxp[c >> 1] = ox;
      ozp[c >> 1] = oz;
    }
  }
  __syncthreads();

  {
    unsigned* h = (wv < 2) ? histX : histZ;
    int t2 = tid & 127;
    int wb = t2 * 8;
    unsigned run = 0;
#pragma unroll
    for (int c = 0; c < 8; ++c) {
      int w = hsw(wb + c);
      unsigned v = h[w];
      unsigned lo = v & 0xFFFFu;
      h[w] = run | ((run + lo) << 16);
      run += lo + (v >> 16);
    }
    unsigned incl = run;
#pragma unroll
    for (int d = 1; d < 64; d <<= 1) {
      unsigned o = (unsigned)__shfl_up((int)incl, d, 64);
      if (lane >= d) incl += o;
    }
    if (lane == 63) xch[16 + wv] = incl;
    __syncthreads();
    unsigned base = incl - run;
    if (wv & 1) base += xch[16 + (wv - 1)];
    unsigned add = base * 0x10001u;
#pragma unroll
    for (int c = 0; c < 8; ++c) h[hsw(wb + c)] += add;
  }
  __syncthreads();

#pragma unroll
  for (int c = 0; c < 16; ++c) {
    unsigned qxv = (xw[c >> 1] >> ((c & 1) * 16)) & 0xFFFFu;
    unsigned qzv = (zw[c >> 1] >> ((c & 1) * 16)) & 0xFFFFu;
    unsigned bx = (unsigned)(int)fminf(
        fmaxf(((float)(int)qxv - lox) * scx, 0.0f), (float)(NBIN - 1));
    unsigned bz = (unsigned)(int)fminf(
        fmaxf(((float)(int)qzv - loz) * scz, 0.0f), (float)(NBIN - 1));
    unsigned shx = (bx & 1) * 16, shz = (bz & 1) * 16;
    unsigned basex = (histX[hsw((int)(bx >> 1))] >> shx) & 0xFFFFu;
    unsigned basez = (histZ[hsw((int)(bz >> 1))] >> shz) & 0xFFFFu;
    int rx = (int)(basex + ((oxp[c >> 1] >> ((c & 1) * 16)) & 0xFFFFu));
    int rz = (int)(basez + ((ozp[c >> 1] >> ((c & 1) * 16)) & 0xFFFFu));
    int d = rx - rz;
    rsum += d < 0 ? -d : d;
  }
  __syncthreads();
}

// ---------------- fallback finalize (per-block) ----------------
__device__ __forceinline__ void rank_finalize(
    unsigned* xch, unsigned* qstats, float* out, int tid, int lane, int wv,
    int rsum, float pd, unsigned nblocks) {
  unsigned long long* rank_acc = (unsigned long long*)qstats;
  double* pd_acc = (double*)(qstats + 2);
#pragma unroll
  for (int d = 32; d; d >>= 1) {
    rsum += __shfl_xor(rsum, d, 64);
    pd += __shfl_xor(pd, d, 64);
  }
  if (lane == 0) {
    xch[wv] = (unsigned)rsum;
    ((float*)xch)[8 + wv] = pd;
  }
  __syncthreads();
  if (tid == 0) {
    unsigned long long rtot =
        (unsigned long long)xch[0] + xch[1] + xch[2] + xch[3];
    float ptot = ((float*)xch)[8] + ((float*)xch)[9] + ((float*)xch)[10] +
                 ((float*)xch)[11];
    atomicAdd(rank_acc, rtot);
    atomicAdd(pd_acc, (double)ptot);
    __threadfence();
    unsigned old = atomicAdd(&qstats[ST_DONE], 1u);
    if (old == nblocks - 1u) {
      unsigned long long rall = atomicAdd(rank_acc, 0ull);
      double pall = atomicAdd(pd_acc, 0.0);
      double inv = 1.0 / ((double)N * (double)N);
      double rank_loss = (double)rall * inv / 32.0;  // K = 32
      double pdv = pall * inv / (2048.0 * 2048.0);   // undo q scaling
      out[0] = (float)(rank_loss + 0.5 * pdv);
      out[1] = (float)rank_loss;
      out[2] = (float)pdv;
    }
  }
}

// ---------------- fallback rank kernel (r0 verbatim, RPB=4) -------------
__global__ __launch_bounds__(256) void rank_kernel(
    const unsigned short* __restrict__ qx,
    const unsigned short* __restrict__ qz, unsigned* __restrict__ qstats,
    float* __restrict__ out) {
  __shared__ unsigned histX[NWRD];
  __shared__ unsigned histZ[NWRD];
  __shared__ unsigned xch[32];

  int tid = threadIdx.x, lane = tid & 63, wv = tid >> 6;
  int row0 = (int)blockIdx.x * RPB;

  float lox = (float)(int)qstats[ST_MIN + 0];
  float scx = (float)(NBIN - 1) /
              (float)(int)max(1u, qstats[ST_MAX + 0] - qstats[ST_MIN + 0]);
  float loz = (float)(int)qstats[ST_MIN + 1];
  float scz = (float)(NBIN - 1) /
              (float)(int)max(1u, qstats[ST_MAX + 1] - qstats[ST_MIN + 1]);

  const uint4* px = (const uint4*)(qx + (size_t)row0 * N);
  const uint4* pz = (const uint4*)(qz + (size_t)row0 * N);

  uint4 cxa = px[tid * 2], cxb = px[tid * 2 + 1];
  uint4 cza = pz[tid * 2], czb = pz[tid * 2 + 1];

  float pd = 0.f;
  int rsum = 0;

#pragma unroll 1
  for (int r = 0; r < RPB; ++r) {
#pragma unroll
    for (int i = 0; i < 4; ++i) {
      histX[tid + 256 * i] = 0u;
      histZ[tid + 256 * i] = 0u;
    }
    uint4 nxa = cxa, nxb = cxb, nza = cza, nzb = czb;
    if (r + 1 < RPB) {
      const uint4* npx = px + (size_t)(r + 1) * (N / 8);
      const uint4* npz = pz + (size_t)(r + 1) * (N / 8);
      nxa = npx[tid * 2];
      nxb = npx[tid * 2 + 1];
      nza = npz[tid * 2];
      nzb = npz[tid * 2 + 1];
    }
    unsigned xw[8] = {cxa.x, cxa.y, cxa.z, cxa.w, cxb.x, cxb.y, cxb.z, cxb.w};
    unsigned zw[8] = {cza.x, cza.y, cza.z, cza.w, czb.x, czb.y, czb.z, czb.w};
    rank_row(xw, zw, histX, histZ, xch, lox, scx, loz, scz, tid, lane, wv, pd,
             rsum);
    cxa = nxa;
    cxb = nxb;
    cza = nza;
    czb = nzb;
  }
  rank_finalize(xch, qstats, out, tid, lane, wv, rsum, pd,
                (unsigned)gridDim.x);
}

// ==================== fused cooperative kernel (512 thr) ================
__global__ __launch_bounds__(TPB) void fused_kernel(
    const float* __restrict__ x, const float* __restrict__ z,
    __hip_bfloat16* __restrict__ xb, __hip_bfloat16* __restrict__ zb,
    float* __restrict__ nx, float* __restrict__ nz,
    unsigned short* __restrict__ qx, unsigned short* __restrict__ qz,
    unsigned* __restrict__ qstats, float* __restrict__ out) {
  __shared__ alignas(16) char smem[65536];
  cg::grid_group grid = cg::this_grid();

  int tid = threadIdx.x;  // 0..511
  int bid = (int)blockIdx.x;
  int lane = tid & 63, wv8 = tid >> 6;

  // ---------------- phase 1: prep (16 rows/block via 8 waves) -----------
  if (bid == 0 && tid < 9)
    qstats[tid] = (tid == 6 || tid == 7) ? 0xFFFFFFFFu : 0u;

#pragma unroll
  for (int rr = 0; rr < 2; ++rr)
    prep_rows(x, z, xb, zb, nx, nz, bid * 16 + rr * 8 + wv8, lane);

  grid.sync();  // prep outputs + qstats init visible device-wide

  // ---------------- phase 2: gram, balanced z/x assignment --------------
  if (bid >= 16) {
    int j = bid - 16;
    int nzt = (j < 48) ? 3 : 2;
    for (int q = 0; q < nzt; ++q) {
      int by, bx;
      tri_decode(j + q * 240, by, bx);
      gram_tile512(zb, nz, qz, DZ, 2048.0f, qstats, 1, by, bx, smem);
      __syncthreads();
    }
  }
  {
    int nxt = (bid < 16) ? 3 : 2;
    for (int q = 0; q < nxt; ++q) {
      int by, bx;
      tri_decode(bid + q * 256, by, bx);
      gram_tile512(xb, nx, qx, DX, 1024.0f, qstats, 0, by, bx, smem);
      __syncthreads();
    }
  }

  grid.sync();  // qx/qz + min/max stats visible device-wide

  // ---------------- phase 3: rank (2 teams x 8 rows) --------------------
  int team = tid >> 8;        // 0,1
  int t = tid & 255;          // team-local tid
  int tlane = t & 63, twv = t >> 6;

  unsigned* histX = (unsigned*)(smem + team * 16384);
  unsigned* histZ = (unsigned*)(smem + team * 16384 + 4096);
  unsigned* xch = (unsigned*)(smem + 32768 + team * 128);
  unsigned* sc = (unsigned*)(smem + 33024);

  // coherent scale fetch (atomic rtn read -> LDS stash -> broadcast)
  if (tid < 4) sc[tid] = atomicAdd(&qstats[ST_MAX + tid], 0u);
  __syncthreads();
  unsigned maxx_ = sc[0], maxz_ = sc[1], minx_ = sc[2], minz_ = sc[3];
  __syncthreads();
  float lox = (float)(int)minx_;
  float scx = (float)(NBIN - 1) / (float)(int)max(1u, maxx_ - minx_);
  float loz = (float)(int)minz_;
  float scz = (float)(NBIN - 1) / (float)(int)max(1u, maxz_ - minz_);

  int row0 = bid * 16 + team * 8;
  const uint4* px = (const uint4*)(qx + (size_t)row0 * N);
  const uint4* pz = (const uint4*)(qz + (size_t)row0 * N);

  uint4 cxa = px[t * 2], cxb = px[t * 2 + 1];
  uint4 cza = pz[t * 2], czb = pz[t * 2 + 1];

  float pd = 0.f;
  int rsum = 0;

#pragma unroll 1
  for (int r = 0; r < 8; ++r) {
#pragma unroll
    for (int i = 0; i < 4; ++i) {
      histX[t + 256 * i] = 0u;
      histZ[t + 256 * i] = 0u;
    }
    uint4 nxa = cxa, nxb = cxb, nza = cza, nzb = czb;
    if (r + 1 < 8) {
      const uint4* npx = px + (size_t)(r + 1) * (N / 8);
      const uint4* npz = pz + (size_t)(r + 1) * (N / 8);
      nxa = npx[t * 2];
      nxb = npx[t * 2 + 1];
      nza = npz[t * 2];
      nzb = npz[t * 2 + 1];
    }
    unsigned xw[8] = {cxa.x, cxa.y, cxa.z, cxa.w, cxb.x, cxb.y, cxb.z, cxb.w};
    unsigned zw[8] = {cza.x, cza.y, cza.z, cza.w, czb.x, czb.y, czb.z, czb.w};
    rank_row(xw, zw, histX, histZ, xch, lox, scx, loz, scz, t, tlane, twv, pd,
             rsum);
    cxa = nxa;
    cxb = nxb;
    cza = nza;
    czb = nzb;
  }

  // combined finalize: team wave-reduce -> LDS -> single block atomics
#pragma unroll
  for (int d = 32; d; d >>= 1) {
    rsum += __shfl_xor(rsum, d, 64);
    pd += __shfl_xor(pd, d, 64);
  }
  if (tlane == 0) {
    xch[twv] = (unsigned)rsum;
    ((float*)xch)[8 + twv] = pd;
  }
  __syncthreads();
  if (tid == 0) {
    unsigned* xch0 = (unsigned*)(smem + 32768);
    unsigned* xch1 = (unsigned*)(smem + 32768 + 128);
    unsigned long long rtot = 0;
    float ptot = 0.f;
#pragma unroll
    for (int k = 0; k < 4; ++k) {
      rtot += (unsigned long long)xch0[k] + xch1[k];
      ptot += ((float*)xch0)[8 + k] + ((float*)xch1)[8 + k];
    }
    unsigned long long* rank_acc = (unsigned long long*)qstats;
    double* pd_acc = (double*)(qstats + 2);
    atomicAdd(rank_acc, rtot);
    atomicAdd(pd_acc, (double)ptot);
    __threadfence();
    unsigned old = atomicAdd(&qstats[ST_DONE], 1u);
    if (old == (unsigned)CGRID - 1u) {
      unsigned long long rall = atomicAdd(rank_acc, 0ull);
      double pall = atomicAdd(pd_acc, 0.0);
      double inv = 1.0 / ((double)N * (double)N);
      double rank_loss = (double)rall * inv / 32.0;  // K = 32
      double pdv = pall * inv / (2048.0 * 2048.0);   // undo q scaling
      out[0] = (float)(rank_loss + 0.5 * pdv);
      out[1] = (float)rank_loss;
      out[2] = (float)pdv;
    }
  }
}

// ---------------- launch ----------------
extern "C" void kernel_launch(void* const* d_in, const int* in_sizes, int n_in,
                              void* d_out, int out_size, void* d_ws,
                              size_t ws_size, hipStream_t stream) {
  (void)in_sizes; (void)n_in; (void)out_size; (void)ws_size;
  const float* x = (const float*)d_in[0];
  const float* z = (const float*)d_in[1];
  float* out = (float*)d_out;

  char* w = (char*)d_ws;
  unsigned short* qx16 = (unsigned short*)(w);             // 32 MB
  unsigned short* qz16 = (unsigned short*)(w + 33554432);  // 32 MB
  __hip_bfloat16* xb = (__hip_bfloat16*)(w + 67108864);    // 4 MB
  __hip_bfloat16* zb = (__hip_bfloat16*)(w + 71303168);    // 0.5 MB
  float* nx = (float*)(w + 71827456);
  float* nz = (float*)(w + 71843840);
  unsigned* qstats = (unsigned*)(w + 71860224);

  // one-time cooperative-capacity check (host-side queries; capture-safe)
  static int coop_ok = -1;
  if (coop_ok < 0) {
    int dev = 0, ncu = 0, nb = 0;
    (void)hipGetDevice(&dev);
    (void)hipDeviceGetAttribute(&ncu, hipDeviceAttributeMultiprocessorCount,
                                dev);
    (void)hipOccupancyMaxActiveBlocksPerMultiprocessor(&nb, fused_kernel, TPB,
                                                       0);
    coop_ok = (nb >= 1 && (long)nb * (long)ncu >= (long)CGRID) ? 1 : 0;
  }

  if (coop_ok) {
    void* args[] = {(void*)&x,      (void*)&z,    (void*)&xb,   (void*)&zb,
                    (void*)&nx,     (void*)&nz,   (void*)&qx16, (void*)&qz16,
                    (void*)&qstats, (void*)&out};
    hipError_t e = hipLaunchCooperativeKernel((const void*)fused_kernel,
                                              dim3(CGRID), dim3(TPB), args, 0,
                                              stream);
    if (e == hipSuccess) return;
    coop_ok = 0;  // permanent fallback from here on
  }

  // fallback: proven r0 three-kernel path (168 us, absmax 0.0)
  prep_kernel<<<N / 4, 256, 0, stream>>>(x, z, xb, zb, nx, nz, qstats);
  gram_both_kernel<<<NTRI, 256, 0, stream>>>(xb, zb, nx, nz, qx16, qz16,
                                             qstats);
  rank_kernel<<<N / RPB, 256, 0, stream>>>(qx16, qz16, qstats, out);
}

// Round 8
// 168.406 us; speedup vs baseline: 2.2948x; 1.0069x over previous
//
#include <hip/hip_runtime.h>
#include <hip/hip_bf16.h>
#include <hip/hip_cooperative_groups.h>

namespace cg = cooperative_groups;

// Problem: N=4096, Dx=512, Dz=64.
// out[0]=total, out[1]=rank_loss, out[2]=pairdist_loss (f32).
//
// ROUND-8: fused coop kernel (CGRID=256 x 512 thr) with 4-TEAM rank.
// Session model (r0/r3/r4): rank time = gens x (35 + 6*RPB) us per
// CU-generation of 4 PARALLEL CHAINS. r7 ran rank as 2 teams x 8 rows
// (2 chains/CU) -> ~83 us phase; r0's 58.8 was 4 chains x 4 rows.
// Fix: phase 3 = 4 teams x 128 thr x 4 rows (hist pair 8 KB/team,
// 32 KB total). Scan simplifies: each team wave scans one full hist
// (64 lanes x 16 words), no cross-wave exchange. Gram (8-wave 2x4
// remap) + prep + guarded launch + r0 fallback: verbatim from r7.

#define N 4096
#define DX 512
#define DZ 64
#define NBIN 2048
#define NWRD (NBIN / 2)
#define RPB 4   // fallback rank kernel (r0 config)
#define CGRID 256
#define TPB 512

typedef __attribute__((ext_vector_type(8))) short short8;
typedef __attribute__((ext_vector_type(4))) float float4v;

// qstats word layout (u32 index):
//   [0..1] rank_acc (u64)  [2..3] pd_acc (double)
//   [4] maxx [5] maxz      [6] minx [7] minz    [8] done-counter
#define ST_MAX 4
#define ST_MIN 6
#define ST_DONE 8

// ---------------- async 16B global -> LDS ----------------
__device__ __forceinline__ void async16(const void* g, void* l) {
  __builtin_amdgcn_global_load_lds(
      (const __attribute__((address_space(1))) unsigned int*)(g),
      (__attribute__((address_space(3))) unsigned int*)(l), 16, 0, 0);
}

// ---------------- prep body (one row per wave) ----------------
__device__ __forceinline__ void prep_rows(
    const float* __restrict__ x, const float* __restrict__ z,
    __hip_bfloat16* __restrict__ xb, __hip_bfloat16* __restrict__ zb,
    float* __restrict__ nx, float* __restrict__ nz, int row, int lane) {
  const float4* xr = (const float4*)(x + (size_t)row * DX);
  float4 a = xr[lane];
  float4 b = xr[lane + 64];
  float s = a.x * a.x + a.y * a.y + a.z * a.z + a.w * a.w +
            b.x * b.x + b.y * b.y + b.z * b.z + b.w * b.w;
#pragma unroll
  for (int d = 32; d; d >>= 1) s += __shfl_xor(s, d, 64);
  if (lane == 0) nx[row] = s;

  ushort4 pa, pb;
  pa.x = __bfloat16_as_ushort(__float2bfloat16(a.x));
  pa.y = __bfloat16_as_ushort(__float2bfloat16(a.y));
  pa.z = __bfloat16_as_ushort(__float2bfloat16(a.z));
  pa.w = __bfloat16_as_ushort(__float2bfloat16(a.w));
  pb.x = __bfloat16_as_ushort(__float2bfloat16(b.x));
  pb.y = __bfloat16_as_ushort(__float2bfloat16(b.y));
  pb.z = __bfloat16_as_ushort(__float2bfloat16(b.z));
  pb.w = __bfloat16_as_ushort(__float2bfloat16(b.w));
  ushort4* xbo = (ushort4*)(xb + (size_t)row * DX);
  xbo[lane] = pa;
  xbo[lane + 64] = pb;

  float4 c = {0.f, 0.f, 0.f, 0.f};
  if (lane < 16) c = ((const float4*)(z + (size_t)row * DZ))[lane];
  float sz = c.x * c.x + c.y * c.y + c.z * c.z + c.w * c.w;
#pragma unroll
  for (int d = 32; d; d >>= 1) sz += __shfl_xor(sz, d, 64);
  if (lane == 0) nz[row] = sz;
  if (lane < 16) {
    ushort4 pc;
    pc.x = __bfloat16_as_ushort(__float2bfloat16(c.x));
    pc.y = __bfloat16_as_ushort(__float2bfloat16(c.y));
    pc.z = __bfloat16_as_ushort(__float2bfloat16(c.z));
    pc.w = __bfloat16_as_ushort(__float2bfloat16(c.w));
    ((ushort4*)(zb + (size_t)row * DZ))[lane] = pc;
  }
}

// ---------------- fallback prep kernel (r0 verbatim behavior) -----------
__global__ __launch_bounds__(256) void prep_kernel(
    const float* __restrict__ x, const float* __restrict__ z,
    __hip_bfloat16* __restrict__ xb, __hip_bfloat16* __restrict__ zb,
    float* __restrict__ nx, float* __restrict__ nz,
    unsigned* __restrict__ qstats) {
  int tid = threadIdx.x;
  if (blockIdx.x == 0 && tid < 9)
    qstats[tid] = (tid == 6 || tid == 7) ? 0xFFFFFFFFu : 0u;
  prep_rows(x, z, xb, zb, nx, nz, (int)blockIdx.x * 4 + (tid >> 6), tid & 63);
}

// ------- bf16 MFMA Gram, BK=64/barrier --------
#define TILE 128
#define BK 64     // staged K per barrier (two 32-col sub-tiles)
#define PADW 132  // ctile row stride in u16 (66 words, 8B-aligned b64)
#define NTRI 528

// ---------------- 256-thread gram tile (r0 verbatim, for fallback) ------
__device__ __forceinline__ void gram_tile(
    const __hip_bfloat16* __restrict__ Abf, const float* __restrict__ norms,
    unsigned short* __restrict__ distq, int K, float qscale,
    unsigned* __restrict__ qstats, int slot, int by, int bx, char* smem) {
  unsigned short* ctile = (unsigned short*)smem;
  unsigned* mmx = (unsigned*)smem;

  int tid = threadIdx.x;
  int wave = tid >> 6, lane = tid & 63;
  int wr = wave >> 1, wc = wave & 1;
  int quad = lane >> 4, l15 = lane & 15;

  int rowBase = by * TILE;
  int colBase = bx * TILE;

  float4v acc[4][4];
#pragma unroll
  for (int mi = 0; mi < 4; ++mi)
#pragma unroll
    for (int ni = 0; ni < 4; ++ni) {
      float4v zv = {0.f, 0.f, 0.f, 0.f};
      acc[mi][ni] = zv;
    }

  const char* Ab = (const char*)Abf;
  const size_t rb = (size_t)K * 2;
  int chunk0 = wave * 2, chunk1 = wave * 2 + 1;
  int rl = lane >> 2;
  int cl = (lane & 3) * 16;

  auto stage = [&](int kc, int b) {
#pragma unroll
    for (int h = 0; h < 2; ++h) {
      const char* base = Ab + (size_t)(kc + h * 32) * 2 + cl;
      short* sA = (short*)(smem + b * 32768 + h * 8192);
      short* sB = (short*)(smem + b * 32768 + 16384 + h * 8192);
      async16(base + (size_t)(rowBase + chunk0 * 16 + rl) * rb,
              &sA[chunk0 * 512]);
      async16(base + (size_t)(rowBase + chunk1 * 16 + rl) * rb,
              &sA[chunk1 * 512]);
      async16(base + (size_t)(colBase + chunk0 * 16 + rl) * rb,
              &sB[chunk0 * 512]);
      async16(base + (size_t)(colBase + chunk1 * 16 + rl) * rb,
              &sB[chunk1 * 512]);
    }
  };

  stage(0, 0);
  int ib = 0;
  for (int kc = 0; kc < K; kc += BK, ib ^= 1) {
    __syncthreads();
    if (kc + BK < K) stage(kc + BK, ib ^ 1);

#pragma unroll
    for (int h = 0; h < 2; ++h) {
      const short* As = (const short*)(smem + ib * 32768 + h * 8192);
      const short* Bs = (const short*)(smem + ib * 32768 + 16384 + h * 8192);
      short8 a[4], b[4];
#pragma unroll
      for (int mi = 0; mi < 4; ++mi)
        a[mi] =
            *(const short8*)(&As[(wr * 64 + mi * 16 + l15) * 32 + quad * 8]);
#pragma unroll
      for (int ni = 0; ni < 4; ++ni)
        b[ni] =
            *(const short8*)(&Bs[(wc * 64 + ni * 16 + l15) * 32 + quad * 8]);
#pragma unroll
      for (int mi = 0; mi < 4; ++mi)
#pragma unroll
        for (int ni = 0; ni < 4; ++ni)
          acc[mi][ni] = __builtin_amdgcn_mfma_f32_16x16x32_bf16(
              a[mi], b[ni], acc[mi][ni], 0, 0, 0);
    }
  }
  __syncthreads();

  unsigned mn = 0xFFFFu, mx = 0u;
  unsigned long long qp[4][4];
#pragma unroll
  for (int mi = 0; mi < 4; ++mi) {
#pragma unroll
    for (int ni = 0; ni < 4; ++ni) {
      int colL = wc * 64 + ni * 16 + l15;
      float ncol = norms[colBase + colL];
      unsigned long long pk = 0ull;
#pragma unroll
      for (int r = 0; r < 4; ++r) {
        int rowL = wr * 64 + mi * 16 + quad * 4 + r;
        int row = rowBase + rowL;
        float sq = norms[row] + ncol - 2.0f * acc[mi][ni][r];
        float d = sq > 0.f ? sqrtf(sq) : 0.f;
        if (row == colBase + colL) d = 0.f;
        unsigned q = (unsigned)(d * qscale);
        q = q > 65535u ? 65535u : q;
        ctile[rowL * PADW + colL] = (unsigned short)q;
        pk |= (unsigned long long)q << (16 * r);
        mx = max(mx, q);
        mn = min(mn, (row == colBase + colL) ? 0xFFFFu : q);
      }
      qp[mi][ni] = pk;
    }
  }
  __syncthreads();

  {
    const unsigned* cw = (const unsigned*)ctile;
    int i0 = tid >> 4, k4 = (tid & 15) * 4;
#pragma unroll
    for (int s = 0; s < 8; ++s) {
      int i = s * 16 + i0;
      int wb = i * (PADW / 2) + k4;
      uint4 v;
      v.x = cw[wb + 0];
      v.y = cw[wb + 1];
      v.z = cw[wb + 2];
      v.w = cw[wb + 3];
      *(uint4*)(distq + (size_t)(rowBase + i) * N + colBase + (tid & 15) * 8) =
          v;
    }
  }

  if (by != bx) {
    __syncthreads();
#pragma unroll
    for (int mi = 0; mi < 4; ++mi)
#pragma unroll
      for (int ni = 0; ni < 4; ++ni) {
        int colL = wc * 64 + ni * 16 + l15;
        int rowL0 = wr * 64 + mi * 16 + quad * 4;
        *(unsigned long long*)&ctile[colL * PADW + rowL0] = qp[mi][ni];
      }
    __syncthreads();
    const unsigned* cw = (const unsigned*)ctile;
    int j0 = tid >> 4, k4 = (tid & 15) * 4;
#pragma unroll
    for (int s = 0; s < 8; ++s) {
      int j = s * 16 + j0;
      int wb = j * (PADW / 2) + k4;
      uint4 v;
      v.x = cw[wb + 0];
      v.y = cw[wb + 1];
      v.z = cw[wb + 2];
      v.w = cw[wb + 3];
      *(uint4*)(distq + (size_t)(colBase + j) * N + rowBase + (tid & 15) * 8) =
          v;
    }
  }

#pragma unroll
  for (int d = 32; d; d >>= 1) {
    mn = min(mn, (unsigned)__shfl_xor((int)mn, d, 64));
    mx = max(mx, (unsigned)__shfl_xor((int)mx, d, 64));
  }
  __syncthreads();
  if (lane == 0) {
    mmx[wave] = mn;
    mmx[4 + wave] = mx;
  }
  __syncthreads();
  if (tid == 0) {
    unsigned bmn = min(min(mmx[0], mmx[1]), min(mmx[2], mmx[3]));
    unsigned bmx = max(max(mmx[4], mmx[5]), max(mmx[6], mmx[7]));
    atomicMin(&qstats[ST_MIN + slot], bmn);
    atomicMax(&qstats[ST_MAX + slot], bmx);
  }
}

// ---------------- 512-thread gram tile (fused path, r7 verbatim) --------
__device__ __forceinline__ void gram_tile512(
    const __hip_bfloat16* __restrict__ Abf, const float* __restrict__ norms,
    unsigned short* __restrict__ distq, int K, float qscale,
    unsigned* __restrict__ qstats, int slot, int by, int bx, char* smem) {
  unsigned short* ctile = (unsigned short*)smem;
  unsigned* mmx = (unsigned*)smem;

  int tid = threadIdx.x;  // 0..511
  int wave = tid >> 6, lane = tid & 63;
  int wr = wave >> 2, wc = wave & 3;
  int quad = lane >> 4, l15 = lane & 15;

  int rowBase = by * TILE;
  int colBase = bx * TILE;

  float4v acc[4][2];
#pragma unroll
  for (int mi = 0; mi < 4; ++mi)
#pragma unroll
    for (int ni = 0; ni < 2; ++ni) {
      float4v zv = {0.f, 0.f, 0.f, 0.f};
      acc[mi][ni] = zv;
    }

  const char* Ab = (const char*)Abf;
  const size_t rb = (size_t)K * 2;
  int rl = lane >> 2;
  int cl = (lane & 3) * 16;

  auto stage = [&](int kc, int b) {
#pragma unroll
    for (int h = 0; h < 2; ++h) {
      const char* base = Ab + (size_t)(kc + h * 32) * 2 + cl;
      short* sA = (short*)(smem + b * 32768 + h * 8192);
      short* sB = (short*)(smem + b * 32768 + 16384 + h * 8192);
      async16(base + (size_t)(rowBase + wave * 16 + rl) * rb,
              &sA[wave * 512]);
      async16(base + (size_t)(colBase + wave * 16 + rl) * rb,
              &sB[wave * 512]);
    }
  };

  stage(0, 0);
  int ib = 0;
  for (int kc = 0; kc < K; kc += BK, ib ^= 1) {
    __syncthreads();
    if (kc + BK < K) stage(kc + BK, ib ^ 1);

#pragma unroll
    for (int h = 0; h < 2; ++h) {
      const short* As = (const short*)(smem + ib * 32768 + h * 8192);
      const short* Bs = (const short*)(smem + ib * 32768 + 16384 + h * 8192);
      short8 a[4], b[2];
#pragma unroll
      for (int mi = 0; mi < 4; ++mi)
        a[mi] =
            *(const short8*)(&As[(wr * 64 + mi * 16 + l15) * 32 + quad * 8]);
#pragma unroll
      for (int ni = 0; ni < 2; ++ni)
        b[ni] =
            *(const short8*)(&Bs[(wc * 32 + ni * 16 + l15) * 32 + quad * 8]);
#pragma unroll
      for (int mi = 0; mi < 4; ++mi)
#pragma unroll
        for (int ni = 0; ni < 2; ++ni)
          acc[mi][ni] = __builtin_amdgcn_mfma_f32_16x16x32_bf16(
              a[mi], b[ni], acc[mi][ni], 0, 0, 0);
    }
  }
  __syncthreads();  // all staging reads done before ctile aliasing write

  unsigned mn = 0xFFFFu, mx = 0u;
  unsigned long long qp[4][2];
#pragma unroll
  for (int mi = 0; mi < 4; ++mi) {
#pragma unroll
    for (int ni = 0; ni < 2; ++ni) {
      int colL = wc * 32 + ni * 16 + l15;
      float ncol = norms[colBase + colL];
      unsigned long long pk = 0ull;
#pragma unroll
      for (int r = 0; r < 4; ++r) {
        int rowL = wr * 64 + mi * 16 + quad * 4 + r;
        int row = rowBase + rowL;
        float sq = norms[row] + ncol - 2.0f * acc[mi][ni][r];
        float d = sq > 0.f ? sqrtf(sq) : 0.f;
        if (row == colBase + colL) d = 0.f;
        unsigned q = (unsigned)(d * qscale);
        q = q > 65535u ? 65535u : q;
        ctile[rowL * PADW + colL] = (unsigned short)q;
        pk |= (unsigned long long)q << (16 * r);
        mx = max(mx, q);
        mn = min(mn, (row == colBase + colL) ? 0xFFFFu : q);
      }
      qp[mi][ni] = pk;
    }
  }
  __syncthreads();

  // pass A: 512 threads, 32 rows per iter, 4 iters
  {
    const unsigned* cw = (const unsigned*)ctile;
    int i0 = tid >> 4, k4 = (tid & 15) * 4;
#pragma unroll
    for (int s = 0; s < 4; ++s) {
      int i = s * 32 + i0;
      int wb = i * (PADW / 2) + k4;
      uint4 v;
      v.x = cw[wb + 0];
      v.y = cw[wb + 1];
      v.z = cw[wb + 2];
      v.w = cw[wb + 3];
      *(uint4*)(distq + (size_t)(rowBase + i) * N + colBase + (tid & 15) * 8) =
          v;
    }
  }

  // pass B: mirror tile via transposed restage (off-diag only)
  if (by != bx) {
    __syncthreads();
#pragma unroll
    for (int mi = 0; mi < 4; ++mi)
#pragma unroll
      for (int ni = 0; ni < 2; ++ni) {
        int colL = wc * 32 + ni * 16 + l15;
        int rowL0 = wr * 64 + mi * 16 + quad * 4;
        *(unsigned long long*)&ctile[colL * PADW + rowL0] = qp[mi][ni];
      }
    __syncthreads();
    const unsigned* cw = (const unsigned*)ctile;
    int j0 = tid >> 4, k4 = (tid & 15) * 4;
#pragma unroll
    for (int s = 0; s < 4; ++s) {
      int j = s * 32 + j0;
      int wb = j * (PADW / 2) + k4;
      uint4 v;
      v.x = cw[wb + 0];
      v.y = cw[wb + 1];
      v.z = cw[wb + 2];
      v.w = cw[wb + 3];
      *(uint4*)(distq + (size_t)(colBase + j) * N + rowBase + (tid & 15) * 8) =
          v;
    }
  }

  // block min/max reduce -> 2 device atomics per tile
#pragma unroll
  for (int d = 32; d; d >>= 1) {
    mn = min(mn, (unsigned)__shfl_xor((int)mn, d, 64));
    mx = max(mx, (unsigned)__shfl_xor((int)mx, d, 64));
  }
  __syncthreads();  // ctile/pass reads done; mmx aliasing safe
  if (lane == 0) {
    mmx[wave] = mn;
    mmx[8 + wave] = mx;
  }
  __syncthreads();
  if (tid == 0) {
    unsigned bmn = mmx[0], bmx = mmx[8];
#pragma unroll
    for (int k = 1; k < 8; ++k) {
      bmn = min(bmn, mmx[k]);
      bmx = max(bmx, mmx[8 + k]);
    }
    atomicMin(&qstats[ST_MIN + slot], bmn);
    atomicMax(&qstats[ST_MAX + slot], bmx);
  }
}

// triangular decode: row-major rows by=0..31, len 32-by
__device__ __forceinline__ void tri_decode(int idx, int& by, int& bx) {
  by = (int)((65.0f - sqrtf(4225.0f - 8.0f * (float)idx)) * 0.5f);
  while (((by + 1) * (65 - (by + 1))) / 2 <= idx) ++by;
  while ((by * (65 - by)) / 2 > idx) --by;
  bx = by + (idx - (by * (65 - by)) / 2);
}

// ---------------- fallback gram kernel (r0 verbatim) ----------------
__global__ __launch_bounds__(256) void gram_both_kernel(
    const __hip_bfloat16* __restrict__ xb, const __hip_bfloat16* __restrict__ zb,
    const float* __restrict__ nx, const float* __restrict__ nz,
    unsigned short* __restrict__ qx16, unsigned short* __restrict__ qz16,
    unsigned* __restrict__ qstats) {
  __shared__ alignas(16) char smem[65536];
  int by, bx;
  tri_decode((int)blockIdx.x, by, bx);
  gram_tile(zb, nz, qz16, DZ, 2048.0f, qstats, 1, by, bx, smem);
  __syncthreads();
  gram_tile(xb, nx, qx16, DX, 1024.0f, qstats, 0, by, bx, smem);
}

// ---------------- histogram word swizzle ----------------
__device__ __forceinline__ int hsw(int w) { return w ^ ((w >> 5) & 31); }

// ---------------- rank body: one row on a 256-thread team (fallback) ----
__device__ __forceinline__ void rank_row(
    const unsigned* xw, const unsigned* zw, unsigned* histX, unsigned* histZ,
    unsigned* xch, float lox, float scx, float loz, float scz, int tid,
    int lane, int wv, float& pd, int& rsum) {
#pragma unroll
  for (int c = 0; c < 16; ++c) {
    unsigned qxv = (xw[c >> 1] >> ((c & 1) * 16)) & 0xFFFFu;
    unsigned qzv = (zw[c >> 1] >> ((c & 1) * 16)) & 0xFFFFu;
    float tv = (float)(int)qzv - 2.0f * (float)(int)qxv - 0.5f;
    pd += tv * tv;
  }
  __syncthreads();

  unsigned oxp[8], ozp[8];
#pragma unroll
  for (int c = 0; c < 16; ++c) {
    unsigned qxv = (xw[c >> 1] >> ((c & 1) * 16)) & 0xFFFFu;
    unsigned qzv = (zw[c >> 1] >> ((c & 1) * 16)) & 0xFFFFu;
    unsigned bx = (unsigned)(int)fminf(
        fmaxf(((float)(int)qxv - lox) * scx, 0.0f), (float)(NBIN - 1));
    unsigned bz = (unsigned)(int)fminf(
        fmaxf(((float)(int)qzv - loz) * scz, 0.0f), (float)(NBIN - 1));
    unsigned shx = (bx & 1) * 16, shz = (bz & 1) * 16;
    unsigned ox =
        (atomicAdd(&histX[hsw((int)(bx >> 1))], 1u << shx) >> shx) & 0xFFFFu;
    unsigned oz =
        (atomicAdd(&histZ[hsw((int)(bz >> 1))], 1u << shz) >> shz) & 0xFFFFu;
    if (c & 1) {
      oxp[c >> 1] |= ox << 16;
      ozp[c >> 1] |= oz << 16;
    } else {
      oxp[c >> 1] = ox;
      ozp[c >> 1] = oz;
    }
  }
  __syncthreads();

  {
    unsigned* h = (wv < 2) ? histX : histZ;
    int t2 = tid & 127;
    int wb = t2 * 8;
    unsigned run = 0;
#pragma unroll
    for (int c = 0; c < 8; ++c) {
      int w = hsw(wb + c);
      unsigned v = h[w];
      unsigned lo = v & 0xFFFFu;
      h[w] = run | ((run + lo) << 16);
      run += lo + (v >> 16);
    }
    unsigned incl = run;
#pragma unroll
    for (int d = 1; d < 64; d <<= 1) {
      unsigned o = (unsigned)__shfl_up((int)incl, d, 64);
      if (lane >= d) incl += o;
    }
    if (lane == 63) xch[16 + wv] = incl;
    __syncthreads();
    unsigned base = incl - run;
    if (wv & 1) base += xch[16 + (wv - 1)];
    unsigned add = base * 0x10001u;
#pragma unroll
    for (int c = 0; c < 8; ++c) h[hsw(wb + c)] += add;
  }
  __syncthreads();

#pragma unroll
  for (int c = 0; c < 16; ++c) {
    unsigned qxv = (xw[c >> 1] >> ((c & 1) * 16)) & 0xFFFFu;
    unsigned qzv = (zw[c >> 1] >> ((c & 1) * 16)) & 0xFFFFu;
    unsigned bx = (unsigned)(int)fminf(
        fmaxf(((float)(int)qxv - lox) * scx, 0.0f), (float)(NBIN - 1));
    unsigned bz = (unsigned)(int)fminf(
        fmaxf(((float)(int)qzv - loz) * scz, 0.0f), (float)(NBIN - 1));
    unsigned shx = (bx & 1) * 16, shz = (bz & 1) * 16;
    unsigned basex = (histX[hsw((int)(bx >> 1))] >> shx) & 0xFFFFu;
    unsigned basez = (histZ[hsw((int)(bz >> 1))] >> shz) & 0xFFFFu;
    int rx = (int)(basex + ((oxp[c >> 1] >> ((c & 1) * 16)) & 0xFFFFu));
    int rz = (int)(basez + ((ozp[c >> 1] >> ((c & 1) * 16)) & 0xFFFFu));
    int d = rx - rz;
    rsum += d < 0 ? -d : d;
  }
  __syncthreads();
}

// ---------------- fallback finalize (per-block) ----------------
__device__ __forceinline__ void rank_finalize(
    unsigned* xch, unsigned* qstats, float* out, int tid, int lane, int wv,
    int rsum, float pd, unsigned nblocks) {
  unsigned long long* rank_acc = (unsigned long long*)qstats;
  double* pd_acc = (double*)(qstats + 2);
#pragma unroll
  for (int d = 32; d; d >>= 1) {
    rsum += __shfl_xor(rsum, d, 64);
    pd += __shfl_xor(pd, d, 64);
  }
  if (lane == 0) {
    xch[wv] = (unsigned)rsum;
    ((float*)xch)[8 + wv] = pd;
  }
  __syncthreads();
  if (tid == 0) {
    unsigned long long rtot =
        (unsigned long long)xch[0] + xch[1] + xch[2] + xch[3];
    float ptot = ((float*)xch)[8] + ((float*)xch)[9] + ((float*)xch)[10] +
                 ((float*)xch)[11];
    atomicAdd(rank_acc, rtot);
    atomicAdd(pd_acc, (double)ptot);
    __threadfence();
    unsigned old = atomicAdd(&qstats[ST_DONE], 1u);
    if (old == nblocks - 1u) {
      unsigned long long rall = atomicAdd(rank_acc, 0ull);
      double pall = atomicAdd(pd_acc, 0.0);
      double inv = 1.0 / ((double)N * (double)N);
      double rank_loss = (double)rall * inv / 32.0;  // K = 32
      double pdv = pall * inv / (2048.0 * 2048.0);   // undo q scaling
      out[0] = (float)(rank_loss + 0.5 * pdv);
      out[1] = (float)rank_loss;
      out[2] = (float)pdv;
    }
  }
}

// ---------------- fallback rank kernel (r0 verbatim, RPB=4) -------------
__global__ __launch_bounds__(256) void rank_kernel(
    const unsigned short* __restrict__ qx,
    const unsigned short* __restrict__ qz, unsigned* __restrict__ qstats,
    float* __restrict__ out) {
  __shared__ unsigned histX[NWRD];
  __shared__ unsigned histZ[NWRD];
  __shared__ unsigned xch[32];

  int tid = threadIdx.x, lane = tid & 63, wv = tid >> 6;
  int row0 = (int)blockIdx.x * RPB;

  float lox = (float)(int)qstats[ST_MIN + 0];
  float scx = (float)(NBIN - 1) /
              (float)(int)max(1u, qstats[ST_MAX + 0] - qstats[ST_MIN + 0]);
  float loz = (float)(int)qstats[ST_MIN + 1];
  float scz = (float)(NBIN - 1) /
              (float)(int)max(1u, qstats[ST_MAX + 1] - qstats[ST_MIN + 1]);

  const uint4* px = (const uint4*)(qx + (size_t)row0 * N);
  const uint4* pz = (const uint4*)(qz + (size_t)row0 * N);

  uint4 cxa = px[tid * 2], cxb = px[tid * 2 + 1];
  uint4 cza = pz[tid * 2], czb = pz[tid * 2 + 1];

  float pd = 0.f;
  int rsum = 0;

#pragma unroll 1
  for (int r = 0; r < RPB; ++r) {
#pragma unroll
    for (int i = 0; i < 4; ++i) {
      histX[tid + 256 * i] = 0u;
      histZ[tid + 256 * i] = 0u;
    }
    uint4 nxa = cxa, nxb = cxb, nza = cza, nzb = czb;
    if (r + 1 < RPB) {
      const uint4* npx = px + (size_t)(r + 1) * (N / 8);
      const uint4* npz = pz + (size_t)(r + 1) * (N / 8);
      nxa = npx[tid * 2];
      nxb = npx[tid * 2 + 1];
      nza = npz[tid * 2];
      nzb = npz[tid * 2 + 1];
    }
    unsigned xw[8] = {cxa.x, cxa.y, cxa.z, cxa.w, cxb.x, cxb.y, cxb.z, cxb.w};
    unsigned zw[8] = {cza.x, cza.y, cza.z, cza.w, czb.x, czb.y, czb.z, czb.w};
    rank_row(xw, zw, histX, histZ, xch, lox, scx, loz, scz, tid, lane, wv, pd,
             rsum);
    cxa = nxa;
    cxb = nxb;
    cza = nza;
    czb = nzb;
  }
  rank_finalize(xch, qstats, out, tid, lane, wv, rsum, pd,
                (unsigned)gridDim.x);
}

// ==================== fused cooperative kernel (512 thr) ================
__global__ __launch_bounds__(TPB) void fused_kernel(
    const float* __restrict__ x, const float* __restrict__ z,
    __hip_bfloat16* __restrict__ xb, __hip_bfloat16* __restrict__ zb,
    float* __restrict__ nx, float* __restrict__ nz,
    unsigned short* __restrict__ qx, unsigned short* __restrict__ qz,
    unsigned* __restrict__ qstats, float* __restrict__ out) {
  __shared__ alignas(16) char smem[65536];
  cg::grid_group grid = cg::this_grid();

  int tid = threadIdx.x;  // 0..511
  int bid = (int)blockIdx.x;
  int lane = tid & 63, wv8 = tid >> 6;

  // ---------------- phase 1: prep (16 rows/block via 8 waves) -----------
  if (bid == 0 && tid < 9)
    qstats[tid] = (tid == 6 || tid == 7) ? 0xFFFFFFFFu : 0u;

#pragma unroll
  for (int rr = 0; rr < 2; ++rr)
    prep_rows(x, z, xb, zb, nx, nz, bid * 16 + rr * 8 + wv8, lane);

  grid.sync();  // prep outputs + qstats init visible device-wide

  // ---------------- phase 2: gram, balanced z/x assignment --------------
  if (bid >= 16) {
    int j = bid - 16;
    int nzt = (j < 48) ? 3 : 2;
    for (int q = 0; q < nzt; ++q) {
      int by, bx;
      tri_decode(j + q * 240, by, bx);
      gram_tile512(zb, nz, qz, DZ, 2048.0f, qstats, 1, by, bx, smem);
      __syncthreads();
    }
  }
  {
    int nxt = (bid < 16) ? 3 : 2;
    for (int q = 0; q < nxt; ++q) {
      int by, bx;
      tri_decode(bid + q * 256, by, bx);
      gram_tile512(xb, nx, qx, DX, 1024.0f, qstats, 0, by, bx, smem);
      __syncthreads();
    }
  }

  grid.sync();  // qx/qz + min/max stats visible device-wide

  // ------- phase 3: rank — 4 teams x 128 thr x 4 rows (r0 shape) --------
  int team = tid >> 7;  // 0..3
  int t = tid & 127;    // team-local tid; team's 2 waves are HW-aligned

  unsigned* histX = (unsigned*)(smem + team * 8192);
  unsigned* histZ = (unsigned*)(smem + team * 8192 + 4096);
  unsigned* rs = (unsigned*)(smem + 32768);      // 8 per-wave rsums
  float* pf = (float*)(smem + 32768 + 32);       // 8 per-wave pds
  unsigned* sc = (unsigned*)(smem + 32768 + 64); // scales stash

  // coherent scale fetch (atomic rtn read -> LDS stash -> broadcast)
  if (tid < 4) sc[tid] = atomicAdd(&qstats[ST_MAX + tid], 0u);
  __syncthreads();
  unsigned maxx_ = sc[0], maxz_ = sc[1], minx_ = sc[2], minz_ = sc[3];
  __syncthreads();
  float lox = (float)(int)minx_;
  float scx = (float)(NBIN - 1) / (float)(int)max(1u, maxx_ - minx_);
  float loz = (float)(int)minz_;
  float scz = (float)(NBIN - 1) / (float)(int)max(1u, maxz_ - minz_);

  int row0 = bid * 16 + team * 4;
  const uint4* px = (const uint4*)(qx + (size_t)row0 * N);
  const uint4* pz = (const uint4*)(qz + (size_t)row0 * N);

  // row cache: 4 uint4 per array (128 thr x 32 cols = 4096)
  uint4 cx0 = px[t], cx1 = px[128 + t], cx2 = px[256 + t], cx3 = px[384 + t];
  uint4 cz0 = pz[t], cz1 = pz[128 + t], cz2 = pz[256 + t], cz3 = pz[384 + t];

  float pd = 0.f;
  int rsum = 0;

#pragma unroll 1
  for (int r = 0; r < 4; ++r) {
    // zero team hists (1024 words each, 128 threads)
#pragma unroll
    for (int i = 0; i < 8; ++i) {
      histX[t + 128 * i] = 0u;
      histZ[t + 128 * i] = 0u;
    }
    // prefetch next row
    uint4 nx0 = cx0, nx1 = cx1, nx2 = cx2, nx3 = cx3;
    uint4 nz0 = cz0, nz1 = cz1, nz2 = cz2, nz3 = cz3;
    if (r + 1 < 4) {
      const uint4* npx = px + (size_t)(r + 1) * (N / 8);
      const uint4* npz = pz + (size_t)(r + 1) * (N / 8);
      nx0 = npx[t]; nx1 = npx[128 + t]; nx2 = npx[256 + t]; nx3 = npx[384 + t];
      nz0 = npz[t]; nz1 = npz[128 + t]; nz2 = npz[256 + t]; nz3 = npz[384 + t];
    }

    unsigned xw[16] = {cx0.x, cx0.y, cx0.z, cx0.w, cx1.x, cx1.y, cx1.z, cx1.w,
                       cx2.x, cx2.y, cx2.z, cx2.w, cx3.x, cx3.y, cx3.z, cx3.w};
    unsigned zw[16] = {cz0.x, cz0.y, cz0.z, cz0.w, cz1.x, cz1.y, cz1.z, cz1.w,
                       cz2.x, cz2.y, cz2.z, cz2.w, cz3.x, cz3.y, cz3.z, cz3.w};

    // pairdist (no LDS) before the zeroing barrier
#pragma unroll
    for (int c = 0; c < 32; ++c) {
      unsigned qxv = (xw[c >> 1] >> ((c & 1) * 16)) & 0xFFFFu;
      unsigned qzv = (zw[c >> 1] >> ((c & 1) * 16)) & 0xFFFFu;
      // dz-dx = (qz - 2*qx - 0.5)/2048
      float tv = (float)(int)qzv - 2.0f * (float)(int)qxv - 0.5f;
      pd += tv * tv;
    }
    __syncthreads();  // zeros visible (block-wide; teams in lockstep)

    // count pass: atomic-rtn arrival capture (32 cols/thread)
    unsigned oxp[16], ozp[16];
#pragma unroll
    for (int c = 0; c < 32; ++c) {
      unsigned qxv = (xw[c >> 1] >> ((c & 1) * 16)) & 0xFFFFu;
      unsigned qzv = (zw[c >> 1] >> ((c & 1) * 16)) & 0xFFFFu;
      unsigned bx = (unsigned)(int)fminf(
          fmaxf(((float)(int)qxv - lox) * scx, 0.0f), (float)(NBIN - 1));
      unsigned bz = (unsigned)(int)fminf(
          fmaxf(((float)(int)qzv - loz) * scz, 0.0f), (float)(NBIN - 1));
      unsigned shx = (bx & 1) * 16, shz = (bz & 1) * 16;
      unsigned ox =
          (atomicAdd(&histX[hsw((int)(bx >> 1))], 1u << shx) >> shx) & 0xFFFFu;
      unsigned oz =
          (atomicAdd(&histZ[hsw((int)(bz >> 1))], 1u << shz) >> shz) & 0xFFFFu;
      if (c & 1) {
        oxp[c >> 1] |= ox << 16;
        ozp[c >> 1] |= oz << 16;
      } else {
        oxp[c >> 1] = ox;
        ozp[c >> 1] = oz;
      }
    }
    __syncthreads();

    // dual scan: team wave 0 -> histX, wave 1 -> histZ (64 lanes x 16 wrds)
    {
      unsigned* h = (t < 64) ? histX : histZ;
      int wb = lane * 16;
      unsigned run = 0;
#pragma unroll
      for (int c = 0; c < 16; ++c) {
        int w = hsw(wb + c);
        unsigned v = h[w];
        unsigned lo = v & 0xFFFFu;
        h[w] = run | ((run + lo) << 16);
        run += lo + (v >> 16);
      }
      unsigned incl = run;
#pragma unroll
      for (int d = 1; d < 64; d <<= 1) {
        unsigned o = (unsigned)__shfl_up((int)incl, d, 64);
        if (lane >= d) incl += o;
      }
      unsigned base = incl - run;
      unsigned add = base * 0x10001u;
#pragma unroll
      for (int c = 0; c < 16; ++c) h[hsw(wb + c)] += add;
    }
    __syncthreads();

    // final pass: rank = scanned base + arrival
#pragma unroll
    for (int c = 0; c < 32; ++c) {
      unsigned qxv = (xw[c >> 1] >> ((c & 1) * 16)) & 0xFFFFu;
      unsigned qzv = (zw[c >> 1] >> ((c & 1) * 16)) & 0xFFFFu;
      unsigned bx = (unsigned)(int)fminf(
          fmaxf(((float)(int)qxv - lox) * scx, 0.0f), (float)(NBIN - 1));
      unsigned bz = (unsigned)(int)fminf(
          fmaxf(((float)(int)qzv - loz) * scz, 0.0f), (float)(NBIN - 1));
      unsigned shx = (bx & 1) * 16, shz = (bz & 1) * 16;
      unsigned basex = (histX[hsw((int)(bx >> 1))] >> shx) & 0xFFFFu;
      unsigned basez = (histZ[hsw((int)(bz >> 1))] >> shz) & 0xFFFFu;
      int rx = (int)(basex + ((oxp[c >> 1] >> ((c & 1) * 16)) & 0xFFFFu));
      int rz = (int)(basez + ((ozp[c >> 1] >> ((c & 1) * 16)) & 0xFFFFu));
      int d = rx - rz;
      rsum += d < 0 ? -d : d;
    }
    __syncthreads();  // final reads done before next row's zeroing

    cx0 = nx0; cx1 = nx1; cx2 = nx2; cx3 = nx3;
    cz0 = nz0; cz1 = nz1; cz2 = nz2; cz3 = nz3;
  }

  // finalize: per-wave reduce -> LDS -> single block atomics
#pragma unroll
  for (int d = 32; d; d >>= 1) {
    rsum += __shfl_xor(rsum, d, 64);
    pd += __shfl_xor(pd, d, 64);
  }
  if (lane == 0) {
    rs[wv8] = (unsigned)rsum;
    pf[wv8] = pd;
  }
  __syncthreads();
  if (tid == 0) {
    unsigned long long rtot = 0;
    float ptot = 0.f;
#pragma unroll
    for (int k = 0; k < 8; ++k) {
      rtot += (unsigned long long)rs[k];
      ptot += pf[k];
    }
    unsigned long long* rank_acc = (unsigned long long*)qstats;
    double* pd_acc = (double*)(qstats + 2);
    atomicAdd(rank_acc, rtot);
    atomicAdd(pd_acc, (double)ptot);
    __threadfence();
    unsigned old = atomicAdd(&qstats[ST_DONE], 1u);
    if (old == (unsigned)CGRID - 1u) {
      unsigned long long rall = atomicAdd(rank_acc, 0ull);
      double pall = atomicAdd(pd_acc, 0.0);
      double inv = 1.0 / ((double)N * (double)N);
      double rank_loss = (double)rall * inv / 32.0;  // K = 32
      double pdv = pall * inv / (2048.0 * 2048.0);   // undo q scaling
      out[0] = (float)(rank_loss + 0.5 * pdv);
      out[1] = (float)rank_loss;
      out[2] = (float)pdv;
    }
  }
}

// ---------------- launch ----------------
extern "C" void kernel_launch(void* const* d_in, const int* in_sizes, int n_in,
                              void* d_out, int out_size, void* d_ws,
                              size_t ws_size, hipStream_t stream) {
  (void)in_sizes; (void)n_in; (void)out_size; (void)ws_size;
  const float* x = (const float*)d_in[0];
  const float* z = (const float*)d_in[1];
  float* out = (float*)d_out;

  char* w = (char*)d_ws;
  unsigned short* qx16 = (unsigned short*)(w);             // 32 MB
  unsigned short* qz16 = (unsigned short*)(w + 33554432);  // 32 MB
  __hip_bfloat16* xb = (__hip_bfloat16*)(w + 67108864);    // 4 MB
  __hip_bfloat16* zb = (__hip_bfloat16*)(w + 71303168);    // 0.5 MB
  float* nx = (float*)(w + 71827456);
  float* nz = (float*)(w + 71843840);
  unsigned* qstats = (unsigned*)(w + 71860224);

  // one-time cooperative-capacity check (host-side queries; capture-safe)
  static int coop_ok = -1;
  if (coop_ok < 0) {
    int dev = 0, ncu = 0, nb = 0;
    (void)hipGetDevice(&dev);
    (void)hipDeviceGetAttribute(&ncu, hipDeviceAttributeMultiprocessorCount,
                                dev);
    (void)hipOccupancyMaxActiveBlocksPerMultiprocessor(&nb, fused_kernel, TPB,
                                                       0);
    coop_ok = (nb >= 1 && (long)nb * (long)ncu >= (long)CGRID) ? 1 : 0;
  }

  if (coop_ok) {
    void* args[] = {(void*)&x,      (void*)&z,    (void*)&xb,   (void*)&zb,
                    (void*)&nx,     (void*)&nz,   (void*)&qx16, (void*)&qz16,
                    (void*)&qstats, (void*)&out};
    hipError_t e = hipLaunchCooperativeKernel((const void*)fused_kernel,
                                              dim3(CGRID), dim3(TPB), args, 0,
                                              stream);
    if (e == hipSuccess) return;
    coop_ok = 0;  // permanent fallback from here on
  }

  // fallback: proven r0 three-kernel path (168 us, absmax 0.0)
  prep_kernel<<<N / 4, 256, 0, stream>>>(x, z, xb, zb, nx, nz, qstats);
  gram_both_kernel<<<NTRI, 256, 0, stream>>>(xb, zb, nx, nz, qx16, qz16,
                                             qstats);
  rank_kernel<<<N / RPB, 256, 0, stream>>>(qx16, qz16, qstats, out);
}